// Round 9
// baseline (1602.599 us; speedup 1.0000x reference)
//
#include <hip/hip_runtime.h>
#include <hip/hip_bf16.h>

#define BATCH  32
#define SEQ    1024
#define DMODEL 384
#define DINNER 768
#define DSTATE 16
#define DTRANK 24
#define NTOK   (BATCH * SEQ)
#define TC     32             // time chunks for parallel scan
#define CL     (SEQ / TC)     // 32 steps per chunk
#define DTR_R  32             // tokens per dt block

typedef __hip_bfloat16 bf16;
typedef __attribute__((ext_vector_type(8))) short frag_ab;  // 8 bf16
typedef __attribute__((ext_vector_type(4))) float frag_cd;  // 4 f32

__device__ __forceinline__ float b2f(bf16 v) { return __bfloat162float(v); }
__device__ __forceinline__ bf16  f2b(float v) { return __float2bfloat16(v); }
__device__ __forceinline__ float ldx(const void* p, size_t i, bool f32m) {
    return f32m ? ((const float*)p)[i] : b2f(((const bf16*)p)[i]);
}

// async global->LDS, 16B per lane (wave-uniform LDS base + lane*16)
__device__ __forceinline__ void gld16(void* l, const void* g) {
    __builtin_amdgcn_global_load_lds(
        (const __attribute__((address_space(1))) unsigned int*)g,
        (__attribute__((address_space(3))) unsigned int*)l, 16, 0, 0);
}

// elementwise bf16 product of 8 pairs (f32 math, one rounding)
__device__ __forceinline__ uint4 bmul8(uint4 y, uint4 s) {
    const bf16* yb = (const bf16*)&y;
    const bf16* sb = (const bf16*)&s;
    uint4 r;
    bf16* rb = (bf16*)&r;
#pragma unroll
    for (int j = 0; j < 8; ++j) rb[j] = f2b(b2f(yb[j]) * b2f(sb[j]));
    return r;
}

// ------------------------------------------------------------------
// Input-dtype detection (f32 vs bf16). Verified: inputs are f32.
// ------------------------------------------------------------------
__global__ void detect_kernel(const unsigned short* __restrict__ x, int* flag) {
    int bad = 0;
    for (int i = threadIdx.x; i < 16384; i += 256) {
        int e = (x[i] >> 7) & 0xFF;
        bad |= (e >= 0xE0);
    }
    if (bad) atomicOr(flag, 1);
}

// ------------------------------------------------------------------
// A-structure check: Av[n]/Av[0] == n+1 (A_log = log(1..16) broadcast).
// ------------------------------------------------------------------
__global__ void struct_check(const float* __restrict__ alog, int* flag) {
    int c = blockIdx.x * 256 + threadIdx.x;
    if (c >= DINNER) return;
    float a0 = __expf(alog[c * 16]);
    int bad = 0;
#pragma unroll
    for (int n = 1; n < DSTATE; ++n) {
        float r = __expf(alog[c * 16 + n]) / a0;
        bad |= (fabsf(r - (float)(n + 1)) > 1e-3f * (n + 1));
    }
    if (bad) atomicOr(flag + 1, 1);
}

// ------------------------------------------------------------------
// Weight conversion: small params -> f32, GEMM weights -> bf16.
// ------------------------------------------------------------------
struct CvtF { const void* src[15]; float* dst[15]; int n[15]; };
struct CvtB { const void* src[7];  bf16*  dst[7];  int n[7];  };

__global__ void convert_f_kernel(CvtF p, const int* __restrict__ flag) {
    bool f32m = (*flag != 0);
    int y = blockIdx.y;
    const void* s = p.src[y];
    float* d = p.dst[y];
    int n = p.n[y];
    for (int i = blockIdx.x * 256 + threadIdx.x; i < n; i += gridDim.x * 256)
        d[i] = ldx(s, i, f32m);
}
__global__ void convert_b_kernel(CvtB p, const int* __restrict__ flag) {
    bool f32m = (*flag != 0);
    int y = blockIdx.y;
    const void* s = p.src[y];
    bf16* d = p.dst[y];
    int n = p.n[y];
    for (int i = blockIdx.x * 256 + threadIdx.x; i < n; i += gridDim.x * 256)
        d[i] = f2b(ldx(s, i, f32m));
}

// ------------------------------------------------------------------
// dtw transpose: [768][24] f32 -> [24][768] f32 (coalesced dt_kernel).
// ------------------------------------------------------------------
__global__ void transpose_dtw(const float* __restrict__ w, float* __restrict__ wt) {
    int i = blockIdx.x * 256 + threadIdx.x;
    if (i >= DINNER * DTRANK) return;
    int c = i / DTRANK, r = i % DTRANK;
    wt[r * DINNER + c] = w[i];
}

// ------------------------------------------------------------------
// LayerNorm: one wave per row of 384; writes bf16 xn.
// ------------------------------------------------------------------
__global__ void ln_kernel(const void* __restrict__ x, size_t xoff,
                          const float* __restrict__ gamma, const float* __restrict__ beta,
                          bf16* __restrict__ xn, const int* __restrict__ flag) {
    bool f32m = (*flag != 0);
    int wave = threadIdx.x >> 6;
    int lane = threadIdx.x & 63;
    int row  = blockIdx.x * 4 + wave;
    size_t base = xoff + (size_t)row * DMODEL;
    float v[6];
    float s = 0.f, s2 = 0.f;
#pragma unroll
    for (int i = 0; i < 6; ++i) {
        v[i] = ldx(x, base + lane + i * 64, f32m);
        s += v[i];
        s2 += v[i] * v[i];
    }
#pragma unroll
    for (int off = 32; off >= 1; off >>= 1) {
        s  += __shfl_down(s, off, 64);
        s2 += __shfl_down(s2, off, 64);
    }
    s  = __shfl(s, 0, 64);
    s2 = __shfl(s2, 0, 64);
    float mu   = s / DMODEL;
    float var  = s2 / DMODEL - mu * mu;
    float rstd = rsqrtf(var + 1e-5f);
    bf16* xnr = xn + (size_t)row * DMODEL;
#pragma unroll
    for (int i = 0; i < 6; ++i)
        xnr[lane + i * 64] = f2b((v[i] - mu) * rstd * gamma[lane + i * 64] + beta[lane + i * 64]);
}

// MFMA tile compute: 8 ds_read_b128 + 16 MFMA on one LDS buffer
__device__ __forceinline__ void compute_tile(const bf16 (*Al)[32], const bf16 (*Bl)[32],
                                             frag_cd acc[4][4], int wm, int wn,
                                             int mr, int quad) {
    frag_ab af[4], bfr[4];
#pragma unroll
    for (int r = 0; r < 4; ++r)
        af[r] = *(const frag_ab*)&Al[wm * 64 + r * 16 + mr][quad * 8];
#pragma unroll
    for (int c = 0; c < 4; ++c)
        bfr[c] = *(const frag_ab*)&Bl[wn * 64 + c * 16 + mr][quad * 8];
#pragma unroll
    for (int r = 0; r < 4; ++r)
#pragma unroll
        for (int c = 0; c < 4; ++c)
            acc[r][c] = __builtin_amdgcn_mfma_f32_16x16x32_bf16(af[r], bfr[c], acc[r][c], 0, 0, 0);
}

// ------------------------------------------------------------------
// MFMA bf16 GEMM, 128x128 tile, BK=32, 256 threads (2x2 waves of 64x64).
// C[M,N] = A[M,K] @ W[N,K]^T.  Double-buffered gld16 pipeline (R6).
// R7: XCD-aware 1-D grid decode (verified: GEMMs left top-5, total -33us).
// MODE 1: gate epilogue -> d_out.   MODE 2: f32 store, 56 valid cols.
// MODE 4: in-proj combined: xi bf16 | silu(z) bf16.
// MODE 5: out-proj, A-staging multiplies a = ydir * sz (bf16).
// ------------------------------------------------------------------
template <int MODE>
__global__ __launch_bounds__(256) void gemm_mfma(
    const bf16* __restrict__ A, const bf16* __restrict__ W,
    int K, int lda, int ldw, int nNT,
    bf16* __restrict__ C, int ldc, int cofs,
    float* __restrict__ Cf, bf16* __restrict__ Cz, const bf16* __restrict__ Sz,
    const float* __restrict__ gb, const void* __restrict__ xg, size_t xoff,
    void* __restrict__ outg, const int* __restrict__ flag) {
    __shared__ bf16 Als[2][128][32];
    __shared__ bf16 Bls[2][128][32];
    int tid = threadIdx.x;
    int lane = tid & 63;
    int w = tid >> 6;
    int wm = w & 1, wn = w >> 1;
    // XCD-aware decode (see header comment)
    int wgid = blockIdx.x;
    int mt_lo = wgid & 7;
    int rr_ = wgid >> 3;
    int nt = rr_ % nNT;
    int mt = (rr_ / nNT) * 8 + mt_lo;
    int m0 = mt * 128, n0 = nt * 128;
    int row = tid >> 2, kc = tid & 3;
    int mr = lane & 15, quad = lane >> 4;

    const bf16* Ab0 = A + (size_t)(m0 + row) * lda + kc * 8;
    const bf16* Ab1 = A + (size_t)(m0 + 64 + row) * lda + kc * 8;
    const bf16* Wb0 = W + (size_t)(n0 + row) * ldw + kc * 8;
    const bf16* Wb1 = W + (size_t)(n0 + 64 + row) * ldw + kc * 8;
    const bf16* Zb0 = (MODE == 5) ? (Sz + (size_t)(m0 + row) * DINNER + kc * 8) : nullptr;
    const bf16* Zb1 = (MODE == 5) ? (Sz + (size_t)(m0 + 64 + row) * DINNER + kc * 8) : nullptr;

    frag_cd acc[4][4] = {};
    const int NT = K / 32;   // always even (12 or 24)

    if (MODE == 5) {
        uint4 eya0, eya1, esz0, esz1;   // even-tile regs
        uint4 oya0, oya1, osz0, osz1;   // odd-tile regs
        eya0 = *(const uint4*)(Ab0);      eya1 = *(const uint4*)(Ab1);
        esz0 = *(const uint4*)(Zb0);      esz1 = *(const uint4*)(Zb1);
        oya0 = *(const uint4*)(Ab0 + 32); oya1 = *(const uint4*)(Ab1 + 32);
        osz0 = *(const uint4*)(Zb0 + 32); osz1 = *(const uint4*)(Zb1 + 32);
        // prologue: tile 0 into buf 0
        *(uint4*)&Als[0][row][kc * 8]      = bmul8(eya0, esz0);
        *(uint4*)&Als[0][64 + row][kc * 8] = bmul8(eya1, esz1);
        gld16(&Bls[0][row][kc * 8], Wb0);
        gld16(&Bls[0][64 + row][kc * 8], Wb1);
        __syncthreads();
        for (int t = 0; t < NT; t += 2) {
            int k1 = (t + 1) * 32, k2 = (t + 2) * 32, k3 = (t + 3) * 32;
            *(uint4*)&Als[1][row][kc * 8]      = bmul8(oya0, osz0);
            *(uint4*)&Als[1][64 + row][kc * 8] = bmul8(oya1, osz1);
            gld16(&Bls[1][row][kc * 8], Wb0 + k1);
            gld16(&Bls[1][64 + row][kc * 8], Wb1 + k1);
            if (t + 2 < NT) {
                eya0 = *(const uint4*)(Ab0 + k2); eya1 = *(const uint4*)(Ab1 + k2);
                esz0 = *(const uint4*)(Zb0 + k2); esz1 = *(const uint4*)(Zb1 + k2);
            }
            compute_tile(Als[0], Bls[0], acc, wm, wn, mr, quad);
            __syncthreads();
            if (t + 2 < NT) {
                *(uint4*)&Als[0][row][kc * 8]      = bmul8(eya0, esz0);
                *(uint4*)&Als[0][64 + row][kc * 8] = bmul8(eya1, esz1);
                gld16(&Bls[0][row][kc * 8], Wb0 + k2);
                gld16(&Bls[0][64 + row][kc * 8], Wb1 + k2);
                oya0 = *(const uint4*)(Ab0 + k3); oya1 = *(const uint4*)(Ab1 + k3);
                osz0 = *(const uint4*)(Zb0 + k3); osz1 = *(const uint4*)(Zb1 + k3);
            }
            compute_tile(Als[1], Bls[1], acc, wm, wn, mr, quad);
            __syncthreads();
        }
    } else {
        gld16(&Als[0][row][kc * 8], Ab0);
        gld16(&Als[0][64 + row][kc * 8], Ab1);
        gld16(&Bls[0][row][kc * 8], Wb0);
        gld16(&Bls[0][64 + row][kc * 8], Wb1);
        __syncthreads();
        for (int t = 0; t < NT; t += 2) {
            int k1 = (t + 1) * 32, k2 = (t + 2) * 32;
            gld16(&Als[1][row][kc * 8], Ab0 + k1);
            gld16(&Als[1][64 + row][kc * 8], Ab1 + k1);
            gld16(&Bls[1][row][kc * 8], Wb0 + k1);
            gld16(&Bls[1][64 + row][kc * 8], Wb1 + k1);
            compute_tile(Als[0], Bls[0], acc, wm, wn, mr, quad);
            __syncthreads();
            if (t + 2 < NT) {
                gld16(&Als[0][row][kc * 8], Ab0 + k2);
                gld16(&Als[0][64 + row][kc * 8], Ab1 + k2);
                gld16(&Bls[0][row][kc * 8], Wb0 + k2);
                gld16(&Bls[0][64 + row][kc * 8], Wb1 + k2);
            }
            compute_tile(Als[1], Bls[1], acc, wm, wn, mr, quad);
            __syncthreads();
        }
    }

    bool f32m = (MODE == 1) ? (*flag != 0) : false;
#pragma unroll
    for (int r = 0; r < 4; ++r) {
#pragma unroll
        for (int c = 0; c < 4; ++c) {
#pragma unroll
            for (int reg = 0; reg < 4; ++reg) {
                int gm = m0 + wm * 64 + r * 16 + quad * 4 + reg;
                int gn = n0 + wn * 64 + c * 16 + mr;
                float v = acc[r][c][reg];
                if (MODE == 0 || MODE == 5) {
                    C[(size_t)gm * ldc + cofs + gn] = f2b(v);
                } else if (MODE == 2) {
                    if (gn < DTRANK + 2 * DSTATE) Cf[(size_t)gm * 56 + gn] = v;
                } else if (MODE == 4) {  // combined in-proj: xi | silu(z) bf16
                    if (gn < DINNER) {
                        C[(size_t)gm * DINNER + gn] = f2b(v);
                    } else {
                        float sz = v / (1.f + __expf(-v));
                        Cz[(size_t)gm * DINNER + (gn - DINNER)] = f2b(sz);
                    }
                } else {  // MODE 1 gate: g*yf + (1-g)*yb + x  (A == ycat)
                    float g   = 1.f / (1.f + __expf(-(v + gb[gn])));
                    float yfv = b2f(A[(size_t)gm * DINNER + gn]);
                    float ybv = b2f(A[(size_t)gm * DINNER + DMODEL + gn]);
                    size_t gi = xoff + (size_t)gm * DMODEL + gn;
                    float xv  = f32m ? ((const float*)xg)[gi] : b2f(((const bf16*)xg)[gi]);
                    float rr  = g * yfv + (1.f - g) * ybv + xv;
                    if (f32m) ((float*)outg)[gi] = rr;
                    else      ((bf16*)outg)[gi]  = f2b(rr);
                }
            }
        }
    }
}

// ------------------------------------------------------------------
// Depthwise conv (causal fwd / anti-causal reversed-tap bwd) + SiLU, bf16.
// ------------------------------------------------------------------
__global__ void conv_kernel(const bf16* __restrict__ xi_buf, const float* __restrict__ cw,
                            const float* __restrict__ cb, bf16* __restrict__ xc, int reverse) {
    int g = blockIdx.x * blockDim.x + threadIdx.x;
    int c  = g % DINNER;
    int bl = g / DINNER;
    int l = bl % SEQ;
    int b = bl / SEQ;
    float w[4];
#pragma unroll
    for (int k = 0; k < 4; ++k) w[k] = cw[c * 4 + k];
    const bf16* xi = xi_buf + (size_t)b * SEQ * DINNER + c;
    float acc = cb[c];
    if (!reverse) {
#pragma unroll
        for (int k = 0; k < 4; ++k) {
            int ll = l - 3 + k;
            if (ll >= 0) acc += b2f(xi[(size_t)ll * DINNER]) * w[k];
        }
    } else {
#pragma unroll
        for (int j = 0; j < 4; ++j) {
            int ll = l + j;
            if (ll < SEQ) acc += b2f(xi[(size_t)ll * DINNER]) * w[3 - j];
        }
    }
    xc[(size_t)bl * DINNER + c] = f2b(acc / (1.f + __expf(-acc)));
}

// ------------------------------------------------------------------
// dt precompute (R4-verified): weights pinned in VGPRs, HW softplus.
// ------------------------------------------------------------------
__global__ __launch_bounds__(256, 4) void dt_kernel(const float* __restrict__ xp,
                                                    const float* __restrict__ dtwT,
                                                    const float* __restrict__ dtb,
                                                    float* __restrict__ dtf) {
    __shared__ float4 xps[DTR_R][6];   // 24 xp values per token
    int tid = threadIdx.x;
    int c = blockIdx.y * 256 + tid;
    float w[DTRANK];
#pragma unroll
    for (int r = 0; r < DTRANK; ++r) w[r] = dtwT[r * DINNER + c];
#pragma unroll
    for (int r = 0; r < DTRANK; ++r) asm volatile("" : "+v"(w[r]));  // pin in VGPRs
    float bias = dtb[c];

    size_t row0 = (size_t)blockIdx.x * DTR_R;
    for (int i = tid; i < DTR_R * 6; i += 256) {
        int s = i / 6, q = i % 6;
        xps[s][q] = *(const float4*)(xp + (row0 + s) * 56 + q * 4);
    }
    __syncthreads();

    for (int s = 0; s < DTR_R; s += 2) {
        float a0 = bias, a1 = bias;
#pragma unroll
        for (int q = 0; q < 6; ++q) {
            float4 x0 = xps[s][q];
            float4 x1 = xps[s + 1][q];
            a0 += x0.x * w[q * 4 + 0];  a1 += x1.x * w[q * 4 + 0];
            a0 += x0.y * w[q * 4 + 1];  a1 += x1.y * w[q * 4 + 1];
            a0 += x0.z * w[q * 4 + 2];  a1 += x1.z * w[q * 4 + 2];
            a0 += x0.w * w[q * 4 + 3];  a1 += x1.w * w[q * 4 + 3];
        }
        // hardware softplus: max(x,0) + ln2*log2(1 + 2^(-|x|*log2e))
        float e0 = __builtin_amdgcn_exp2f(fabsf(a0) * -1.44269504f);
        float e1 = __builtin_amdgcn_exp2f(fabsf(a1) * -1.44269504f);
        a0 = fmaxf(a0, 0.f) + 0.69314718f * __builtin_amdgcn_logf(1.f + e0);
        a1 = fmaxf(a1, 0.f) + 0.69314718f * __builtin_amdgcn_logf(1.f + e1);
        dtf[(row0 + s) * DINNER + c]     = a0;
        dtf[(row0 + s + 1) * DINNER + c] = a1;
    }
}

// ------------------------------------------------------------------
// Chunked selective scan. R8: register prefetch pipeline. R7 counters
// showed VGPR=36, 690 cyc/step vs ~150 VALU -> load-latency-bound
// (no lookahead; each step's dt/xc load waited full HBM latency).
// Now: 16-step register buffers (dtA/xcA), next block's loads (dtB/xcB
// + next xps staging values) issued BEFORE the compute loop so they fly
// under ~2400 cycles of compute. All arrays statically indexed.
// ------------------------------------------------------------------
template <int PHASE>
__global__ __launch_bounds__(128, 4) void scan_phase(
        const float* __restrict__ xp, const bf16* __restrict__ xc,
        const float* __restrict__ dtf, const float* __restrict__ Alog,
        const float* __restrict__ Dg, float* __restrict__ states,
        bf16* __restrict__ ydir, int reverse, const int* __restrict__ flag) {
    __shared__ float xps[16][32];
    bool generic = (flag[1] != 0);
    int tid = threadIdx.x;
    int bidx = blockIdx.x;
    int tc  = bidx % TC;
    int cgb = bidx / TC;       // bb*6+cg
    int cg  = cgb % 6;
    int bb  = cgb / 6;
    int c = cg * 128 + tid;

    float Av0 = -__expf(Alog[c * DSTATE]);
    float Av[DSTATE];
    if (generic) {
#pragma unroll
        for (int n = 0; n < DSTATE; ++n) Av[n] = -__expf(Alog[c * DSTATE + n]);
    }
    float Dv = Dg[c];

    float h[DSTATE];
    float Q = 1.f, Pg[DSTATE];
    size_t sbase = (size_t)bidx * 32;
    if (PHASE == 0) {
#pragma unroll
        for (int n = 0; n < DSTATE; ++n) { h[n] = 0.f; Pg[n] = 1.f; }
    } else {
#pragma unroll
        for (int n = 0; n < DSTATE; ++n) h[n] = states[(sbase + n) * 128 + tid];
    }

    const size_t brow = (size_t)bb * SEQ;
    const int t0 = tc * CL;
    const int tr0 = reverse ? (SEQ - 1 - t0) : t0;
    const long dstep = reverse ? -(long)DINNER : (long)DINNER;
    const float* pdt = dtf + (brow + tr0) * DINNER + c;
    const bf16*  pxc = xc  + (brow + tr0) * DINNER + c;
    bf16* pyd = (PHASE == 1) ? (ydir + (brow + tr0) * DINNER + c) : nullptr;

    // xp staging address for element i of stage-block starting at g0
    auto xpaddr = [&](int g0, int i) {
        int s = i >> 5, r = i & 31;
        int t = t0 + g0 + s;
        int tr = reverse ? (SEQ - 1 - t) : t;
        return xp + (brow + tr) * 56 + 24 + r;
    };

    // prologue: prefetch block 0 operands + block 0 staging values
    float dtA[16];
    unsigned short xcA[16];
#pragma unroll
    for (int s = 0; s < 16; ++s) {
        dtA[s] = *pdt;  pdt += dstep;
        xcA[s] = *(const unsigned short*)pxc;  pxc += dstep;
    }
    float xpr[4];
#pragma unroll
    for (int j = 0; j < 4; ++j) xpr[j] = *xpaddr(0, tid + j * 128);

    for (int g0 = 0; g0 < CL; g0 += 16) {
        __syncthreads();   // previous compute done reading xps
#pragma unroll
        for (int j = 0; j < 4; ++j) {
            int i = tid + j * 128;
            xps[i >> 5][i & 31] = xpr[j];
        }
        __syncthreads();
        const bool more = (g0 + 16 < CL);
        float dtB[16];
        unsigned short xcB[16];
        if (more) {
#pragma unroll
            for (int s = 0; s < 16; ++s) {
                dtB[s] = *pdt;  pdt += dstep;
                xcB[s] = *(const unsigned short*)pxc;  pxc += dstep;
            }
#pragma unroll
            for (int j = 0; j < 4; ++j) xpr[j] = *xpaddr(g0 + 16, tid + j * 128);
        }
#pragma unroll
        for (int s = 0; s < 16; ++s) {
            float dt  = dtA[s];
            float xcv = b2f(*(const bf16*)&xcA[s]);
            float dtx = dt * xcv;
            float accv = 0.f;
            if (!generic) {
                float e1 = __expf(dt * Av0);
                float d = e1;
#pragma unroll
                for (int n = 0; n < DSTATE; ++n) {
                    h[n] = d * h[n] + dtx * xps[s][n];
                    if (PHASE == 1) accv += h[n] * xps[s][16 + n];
                    d *= e1;
                }
                if (PHASE == 0) Q *= e1;
            } else {
#pragma unroll
                for (int n = 0; n < DSTATE; ++n) {
                    float dA = __expf(dt * Av[n]);
                    h[n] = dA * h[n] + dtx * xps[s][n];
                    if (PHASE == 0) Pg[n] *= dA;
                    else accv += h[n] * xps[s][16 + n];
                }
            }
            if (PHASE == 1) {
                *pyd = f2b(accv + xcv * Dv);
                pyd += dstep;
            }
        }
        if (more) {
#pragma unroll
            for (int s = 0; s < 16; ++s) { dtA[s] = dtB[s]; xcA[s] = xcB[s]; }
        }
    }
    if (PHASE == 0) {
        if (!generic) {
            float d = Q;
#pragma unroll
            for (int n = 0; n < DSTATE; ++n) { Pg[n] = d; d *= Q; }
        }
#pragma unroll
        for (int n = 0; n < DSTATE; ++n) {
            states[(sbase + n) * 128 + tid]      = Pg[n];
            states[(sbase + 16 + n) * 128 + tid] = h[n];
        }
    }
}

__global__ void scan_stitch(float* __restrict__ states) {
    int tid = threadIdx.x;
    int cgb = blockIdx.x;
    float h[DSTATE];
#pragma unroll
    for (int n = 0; n < DSTATE; ++n) h[n] = 0.f;
    for (int tc = 0; tc < TC; ++tc) {
        size_t base = ((size_t)cgb * TC + tc) * 32;
#pragma unroll
        for (int n = 0; n < DSTATE; ++n) {
            float Pv = states[(base + n) * 128 + tid];
            float ev = states[(base + 16 + n) * 128 + tid];
            states[(base + n) * 128 + tid] = h[n];   // h_in for this chunk
            h[n] = Pv * h[n] + ev;
        }
    }
}

// ------------------------------------------------------------------
extern "C" void kernel_launch(void* const* d_in, const int* in_sizes, int n_in,
                              void* d_out, int out_size, void* d_ws, size_t ws_size,
                              hipStream_t stream) {
    (void)n_in; (void)out_size;
    bool dict_order = (in_sizes[4] < 2048);
    int fbase = dict_order ? 5 : 3;
    int bbase = dict_order ? 14 : 12;
    int gwi = dict_order ? 3 : 21;
    int gbi = dict_order ? 4 : 22;

    auto al = [](size_t b) { return (b + 255) & ~(size_t)255; };
    char* ws = (char*)d_ws;
    size_t off = 0;
    auto alloc = [&](size_t bytes) {
        void* p = ws + off;
        off += al(bytes);
        return p;
    };

    int* flag = (int*)alloc(256);

    CvtF pf{};
    int cf = 0;
    auto addf = [&](int idx, int n) {
        float* d = (float*)alloc((size_t)n * 4);
        pf.src[cf] = d_in[idx]; pf.dst[cf] = d; pf.n[cf] = n; ++cf;
        return d;
    };
    float* ln_gc   = addf(1, DMODEL);
    float* ln_bc   = addf(2, DMODEL);
    float* gate_bc = addf(gbi, DMODEL);
    float* convw_f[2], *convb_f[2], *dtw_f[2], *dtb_f[2], *alog_f[2], *dd_f[2];
    for (int d = 0; d < 2; ++d) {
        int base = d ? bbase : fbase;
        convw_f[d] = addf(base + 1, DINNER * 4);
        convb_f[d] = addf(base + 2, DINNER);
        dtw_f[d]   = addf(base + 4, DINNER * DTRANK);
        dtb_f[d]   = addf(base + 5, DINNER);
        alog_f[d]  = addf(base + 6, DINNER * DSTATE);
        dd_f[d]    = addf(base + 7, DINNER);
    }

    CvtB pb{};
    int cb = 0;
    auto addb = [&](int idx, int n, size_t alloc_n) {
        bf16* d = (bf16*)alloc(alloc_n * 2);
        pb.src[cb] = d_in[idx]; pb.dst[cb] = d; pb.n[cb] = n; ++cb;
        return d;
    };
    bf16* gate_wb = addb(gwi, DMODEL * 2 * DMODEL, (size_t)DMODEL * 2 * DMODEL);
    bf16 *inw_b[2], *xpw_b[2], *outw_b[2];
    for (int d = 0; d < 2; ++d) {
        int base = d ? bbase : fbase;
        inw_b[d]  = addb(base + 0, 2 * DINNER * DMODEL, (size_t)2 * DINNER * DMODEL);
        xpw_b[d]  = addb(base + 3, 56 * DINNER, (size_t)128 * DINNER);  // padded
        outw_b[d] = addb(base + 8, DMODEL * DINNER, (size_t)DMODEL * DINNER);
    }

    // transposed dt weights (f32, [24][768]) for coalesced dt_kernel
    float* dtwT_f[2];
    for (int d = 0; d < 2; ++d)
        dtwT_f[d] = (float*)alloc((size_t)DTRANK * DINNER * 4);

    size_t fixed = off;

    // per-chunk activations (silu(z) stored bf16)
    auto chunk_need = [&](int bc) {
        size_t T = (size_t)bc * SEQ;
        return al(T * DMODEL * 2)                       // xn
             + 2 * al(T * DINNER * 2)                   // xi(/ydir), xc
             + al(T * 56 * 4)                           // xp f32
             + al(T * DINNER * 4)                       // dt f32
             + al(T * DINNER * 2)                       // silu(z) bf16
             + al(T * DINNER * 2)                       // ycat
             + al((size_t)bc * 6 * TC * 32 * 128 * 4);  // scan states
    };
    int Bc = 32;
    while (Bc > 1 && fixed + chunk_need(Bc) > ws_size) Bc >>= 1;
    size_t T = (size_t)Bc * SEQ;
    int nMT = (int)(T / 128);   // M tiles; = 8*Bc, divisible by 8

    bf16*  xn_c   = (bf16*)alloc(T * DMODEL * 2);
    bf16*  xib    = (bf16*)alloc(T * DINNER * 2);
    bf16*  xcb    = (bf16*)alloc(T * DINNER * 2);
    float* xpb    = (float*)alloc(T * 56 * 4);
    float* dtfb   = (float*)alloc(T * DINNER * 4);
    bf16*  zbb    = (bf16*)alloc(T * DINNER * 2);
    bf16*  ycat   = (bf16*)alloc(T * DINNER * 2);
    float* states = (float*)alloc((size_t)Bc * 6 * TC * 32 * 128 * 4);
    bf16*  ydir   = xib;  // alias: xi dead after conv

    hipMemsetAsync(flag, 0, 8, stream);
    for (int d = 0; d < 2; ++d)
        hipMemsetAsync(xpw_b[d], 0, (size_t)128 * DINNER * 2, stream);
    detect_kernel<<<1, 256, 0, stream>>>((const unsigned short*)d_in[0], flag);
    convert_f_kernel<<<dim3(8, 15), 256, 0, stream>>>(pf, flag);
    convert_b_kernel<<<dim3(32, 7), 256, 0, stream>>>(pb, flag);
    struct_check<<<3, 256, 0, stream>>>(alog_f[0], flag);
    struct_check<<<3, 256, 0, stream>>>(alog_f[1], flag);
    for (int d = 0; d < 2; ++d)
        transpose_dtw<<<(DINNER * DTRANK + 255) / 256, 256, 0, stream>>>(dtw_f[d], dtwT_f[d]);

    for (int c0 = 0; c0 < BATCH; c0 += Bc) {
        size_t tok0 = (size_t)c0 * SEQ;

        ln_kernel<<<(unsigned)(T / 4), 256, 0, stream>>>(
            d_in[0], tok0 * DMODEL, ln_gc, ln_bc, xn_c, flag);

        for (int dir = 0; dir < 2; ++dir) {
            // combined in-proj: xi (bf16) + silu(z) (bf16), nNT=12
            gemm_mfma<4><<<nMT * 12, 256, 0, stream>>>(
                xn_c, inw_b[dir], DMODEL, DMODEL, DMODEL, 12,
                xib, DINNER, 0, nullptr, zbb, nullptr,
                nullptr, nullptr, 0, nullptr, flag);
            conv_kernel<<<(unsigned)((T * DINNER) / 256), 256, 0, stream>>>(
                xib, convw_f[dir], convb_f[dir], xcb, dir);
            // x-proj (56 cols padded to 128), nNT=1
            gemm_mfma<2><<<nMT * 1, 256, 0, stream>>>(
                xcb, xpw_b[dir], DINNER, DINNER, DINNER, 1,
                nullptr, 0, 0, xpb, nullptr, nullptr,
                nullptr, nullptr, 0, nullptr, flag);
            dt_kernel<<<dim3((unsigned)(T / DTR_R), 3), 256, 0, stream>>>(
                xpb, dtwT_f[dir], dtb_f[dir], dtfb);
            // chunked scan
            scan_phase<0><<<Bc * 6 * TC, 128, 0, stream>>>(
                xpb, xcb, dtfb, alog_f[dir], dd_f[dir], states, nullptr, dir, flag);
            scan_stitch<<<Bc * 6, 128, 0, stream>>>(states);
            scan_phase<1><<<Bc * 6 * TC, 128, 0, stream>>>(
                xpb, xcb, dtfb, alog_f[dir], dd_f[dir], states, ydir, dir, flag);
            // out-proj with fused a = ydir * sz; nNT=3
            gemm_mfma<5><<<nMT * 3, 256, 0, stream>>>(
                ydir, outw_b[dir], DINNER, DINNER, DINNER, 3,
                ycat, DINNER, dir * DMODEL, nullptr, nullptr, zbb,
                nullptr, nullptr, 0, nullptr, flag);
        }

        // gate GEMM + combine + residual, nNT=3
        gemm_mfma<1><<<nMT * 3, 256, 0, stream>>>(
            ycat, gate_wb, DINNER, DINNER, DINNER, 3,
            nullptr, 0, 0, nullptr, nullptr, nullptr,
            gate_bc, d_in[0], tok0 * DMODEL, d_out, flag);
    }
}

// Round 10
// 1265.733 us; speedup vs baseline: 1.2661x; 1.2661x over previous
//
#include <hip/hip_runtime.h>
#include <hip/hip_bf16.h>

#define BATCH  32
#define SEQ    1024
#define DMODEL 384
#define DINNER 768
#define DSTATE 16
#define DTRANK 24
#define NTOK   (BATCH * SEQ)
#define TC     32             // time chunks for parallel scan
#define CL     (SEQ / TC)     // 32 steps per chunk
#define DTR_R  32             // tokens per dt block

typedef __hip_bfloat16 bf16;
typedef __attribute__((ext_vector_type(8))) short frag_ab;  // 8 bf16
typedef __attribute__((ext_vector_type(4))) float frag_cd;  // 4 f32

__device__ __forceinline__ float b2f(bf16 v) { return __bfloat162float(v); }
__device__ __forceinline__ bf16  f2b(float v) { return __float2bfloat16(v); }
__device__ __forceinline__ float ldx(const void* p, size_t i, bool f32m) {
    return f32m ? ((const float*)p)[i] : b2f(((const bf16*)p)[i]);
}

// async global->LDS, 16B per lane (wave-uniform LDS base + lane*16)
__device__ __forceinline__ void gld16(void* l, const void* g) {
    __builtin_amdgcn_global_load_lds(
        (const __attribute__((address_space(1))) unsigned int*)g,
        (__attribute__((address_space(3))) unsigned int*)l, 16, 0, 0);
}

// elementwise bf16 product of 8 pairs (f32 math, one rounding)
__device__ __forceinline__ uint4 bmul8(uint4 y, uint4 s) {
    const bf16* yb = (const bf16*)&y;
    const bf16* sb = (const bf16*)&s;
    uint4 r;
    bf16* rb = (bf16*)&r;
#pragma unroll
    for (int j = 0; j < 8; ++j) rb[j] = f2b(b2f(yb[j]) * b2f(sb[j]));
    return r;
}

// ------------------------------------------------------------------
// Input-dtype detection (f32 vs bf16). Verified: inputs are f32.
// ------------------------------------------------------------------
__global__ void detect_kernel(const unsigned short* __restrict__ x, int* flag) {
    int bad = 0;
    for (int i = threadIdx.x; i < 16384; i += 256) {
        int e = (x[i] >> 7) & 0xFF;
        bad |= (e >= 0xE0);
    }
    if (bad) atomicOr(flag, 1);
}

// ------------------------------------------------------------------
// A-structure check: Av[n]/Av[0] == n+1 (A_log = log(1..16) broadcast).
// ------------------------------------------------------------------
__global__ void struct_check(const float* __restrict__ alog, int* flag) {
    int c = blockIdx.x * 256 + threadIdx.x;
    if (c >= DINNER) return;
    float a0 = __expf(alog[c * 16]);
    int bad = 0;
#pragma unroll
    for (int n = 1; n < DSTATE; ++n) {
        float r = __expf(alog[c * 16 + n]) / a0;
        bad |= (fabsf(r - (float)(n + 1)) > 1e-3f * (n + 1));
    }
    if (bad) atomicOr(flag + 1, 1);
}

// ------------------------------------------------------------------
// Weight conversion: small params -> f32, GEMM weights -> bf16.
// ------------------------------------------------------------------
struct CvtF { const void* src[15]; float* dst[15]; int n[15]; };
struct CvtB { const void* src[7];  bf16*  dst[7];  int n[7];  };

__global__ void convert_f_kernel(CvtF p, const int* __restrict__ flag) {
    bool f32m = (*flag != 0);
    int y = blockIdx.y;
    const void* s = p.src[y];
    float* d = p.dst[y];
    int n = p.n[y];
    for (int i = blockIdx.x * 256 + threadIdx.x; i < n; i += gridDim.x * 256)
        d[i] = ldx(s, i, f32m);
}
__global__ void convert_b_kernel(CvtB p, const int* __restrict__ flag) {
    bool f32m = (*flag != 0);
    int y = blockIdx.y;
    const void* s = p.src[y];
    bf16* d = p.dst[y];
    int n = p.n[y];
    for (int i = blockIdx.x * 256 + threadIdx.x; i < n; i += gridDim.x * 256)
        d[i] = f2b(ldx(s, i, f32m));
}

// ------------------------------------------------------------------
// dtw transpose: [768][24] f32 -> [24][768] f32 (coalesced dt_kernel).
// ------------------------------------------------------------------
__global__ void transpose_dtw(const float* __restrict__ w, float* __restrict__ wt) {
    int i = blockIdx.x * 256 + threadIdx.x;
    if (i >= DINNER * DTRANK) return;
    int c = i / DTRANK, r = i % DTRANK;
    wt[r * DINNER + c] = w[i];
}

// ------------------------------------------------------------------
// LayerNorm: one wave per row of 384; writes bf16 xn.
// ------------------------------------------------------------------
__global__ void ln_kernel(const void* __restrict__ x, size_t xoff,
                          const float* __restrict__ gamma, const float* __restrict__ beta,
                          bf16* __restrict__ xn, const int* __restrict__ flag) {
    bool f32m = (*flag != 0);
    int wave = threadIdx.x >> 6;
    int lane = threadIdx.x & 63;
    int row  = blockIdx.x * 4 + wave;
    size_t base = xoff + (size_t)row * DMODEL;
    float v[6];
    float s = 0.f, s2 = 0.f;
#pragma unroll
    for (int i = 0; i < 6; ++i) {
        v[i] = ldx(x, base + lane + i * 64, f32m);
        s += v[i];
        s2 += v[i] * v[i];
    }
#pragma unroll
    for (int off = 32; off >= 1; off >>= 1) {
        s  += __shfl_down(s, off, 64);
        s2 += __shfl_down(s2, off, 64);
    }
    s  = __shfl(s, 0, 64);
    s2 = __shfl(s2, 0, 64);
    float mu   = s / DMODEL;
    float var  = s2 / DMODEL - mu * mu;
    float rstd = rsqrtf(var + 1e-5f);
    bf16* xnr = xn + (size_t)row * DMODEL;
#pragma unroll
    for (int i = 0; i < 6; ++i)
        xnr[lane + i * 64] = f2b((v[i] - mu) * rstd * gamma[lane + i * 64] + beta[lane + i * 64]);
}

// MFMA tile compute: 8 ds_read_b128 + 16 MFMA on one LDS buffer
__device__ __forceinline__ void compute_tile(const bf16 (*Al)[32], const bf16 (*Bl)[32],
                                             frag_cd acc[4][4], int wm, int wn,
                                             int mr, int quad) {
    frag_ab af[4], bfr[4];
#pragma unroll
    for (int r = 0; r < 4; ++r)
        af[r] = *(const frag_ab*)&Al[wm * 64 + r * 16 + mr][quad * 8];
#pragma unroll
    for (int c = 0; c < 4; ++c)
        bfr[c] = *(const frag_ab*)&Bl[wn * 64 + c * 16 + mr][quad * 8];
#pragma unroll
    for (int r = 0; r < 4; ++r)
#pragma unroll
        for (int c = 0; c < 4; ++c)
            acc[r][c] = __builtin_amdgcn_mfma_f32_16x16x32_bf16(af[r], bfr[c], acc[r][c], 0, 0, 0);
}

// ------------------------------------------------------------------
// MFMA bf16 GEMM, 128x128 tile, BK=32, 256 threads (2x2 waves of 64x64).
// C[M,N] = A[M,K] @ W[N,K]^T.  Double-buffered gld16 pipeline (R6).
// R7: XCD-aware 1-D grid decode (verified: GEMMs left top-5, total -33us).
// MODE 1: gate epilogue -> d_out.   MODE 2: f32 store, 56 valid cols.
// MODE 4: in-proj combined: xi bf16 | silu(z) bf16.
// MODE 5: out-proj, A-staging multiplies a = ydir * sz (bf16).
// ------------------------------------------------------------------
template <int MODE>
__global__ __launch_bounds__(256) void gemm_mfma(
    const bf16* __restrict__ A, const bf16* __restrict__ W,
    int K, int lda, int ldw, int nNT,
    bf16* __restrict__ C, int ldc, int cofs,
    float* __restrict__ Cf, bf16* __restrict__ Cz, const bf16* __restrict__ Sz,
    const float* __restrict__ gb, const void* __restrict__ xg, size_t xoff,
    void* __restrict__ outg, const int* __restrict__ flag) {
    __shared__ bf16 Als[2][128][32];
    __shared__ bf16 Bls[2][128][32];
    int tid = threadIdx.x;
    int lane = tid & 63;
    int w = tid >> 6;
    int wm = w & 1, wn = w >> 1;
    // XCD-aware decode (see header comment)
    int wgid = blockIdx.x;
    int mt_lo = wgid & 7;
    int rr_ = wgid >> 3;
    int nt = rr_ % nNT;
    int mt = (rr_ / nNT) * 8 + mt_lo;
    int m0 = mt * 128, n0 = nt * 128;
    int row = tid >> 2, kc = tid & 3;
    int mr = lane & 15, quad = lane >> 4;

    const bf16* Ab0 = A + (size_t)(m0 + row) * lda + kc * 8;
    const bf16* Ab1 = A + (size_t)(m0 + 64 + row) * lda + kc * 8;
    const bf16* Wb0 = W + (size_t)(n0 + row) * ldw + kc * 8;
    const bf16* Wb1 = W + (size_t)(n0 + 64 + row) * ldw + kc * 8;
    const bf16* Zb0 = (MODE == 5) ? (Sz + (size_t)(m0 + row) * DINNER + kc * 8) : nullptr;
    const bf16* Zb1 = (MODE == 5) ? (Sz + (size_t)(m0 + 64 + row) * DINNER + kc * 8) : nullptr;

    frag_cd acc[4][4] = {};
    const int NT = K / 32;   // always even (12 or 24)

    if (MODE == 5) {
        uint4 eya0, eya1, esz0, esz1;   // even-tile regs
        uint4 oya0, oya1, osz0, osz1;   // odd-tile regs
        eya0 = *(const uint4*)(Ab0);      eya1 = *(const uint4*)(Ab1);
        esz0 = *(const uint4*)(Zb0);      esz1 = *(const uint4*)(Zb1);
        oya0 = *(const uint4*)(Ab0 + 32); oya1 = *(const uint4*)(Ab1 + 32);
        osz0 = *(const uint4*)(Zb0 + 32); osz1 = *(const uint4*)(Zb1 + 32);
        // prologue: tile 0 into buf 0
        *(uint4*)&Als[0][row][kc * 8]      = bmul8(eya0, esz0);
        *(uint4*)&Als[0][64 + row][kc * 8] = bmul8(eya1, esz1);
        gld16(&Bls[0][row][kc * 8], Wb0);
        gld16(&Bls[0][64 + row][kc * 8], Wb1);
        __syncthreads();
        for (int t = 0; t < NT; t += 2) {
            int k1 = (t + 1) * 32, k2 = (t + 2) * 32, k3 = (t + 3) * 32;
            *(uint4*)&Als[1][row][kc * 8]      = bmul8(oya0, osz0);
            *(uint4*)&Als[1][64 + row][kc * 8] = bmul8(oya1, osz1);
            gld16(&Bls[1][row][kc * 8], Wb0 + k1);
            gld16(&Bls[1][64 + row][kc * 8], Wb1 + k1);
            if (t + 2 < NT) {
                eya0 = *(const uint4*)(Ab0 + k2); eya1 = *(const uint4*)(Ab1 + k2);
                esz0 = *(const uint4*)(Zb0 + k2); esz1 = *(const uint4*)(Zb1 + k2);
            }
            compute_tile(Als[0], Bls[0], acc, wm, wn, mr, quad);
            __syncthreads();
            if (t + 2 < NT) {
                *(uint4*)&Als[0][row][kc * 8]      = bmul8(eya0, esz0);
                *(uint4*)&Als[0][64 + row][kc * 8] = bmul8(eya1, esz1);
                gld16(&Bls[0][row][kc * 8], Wb0 + k2);
                gld16(&Bls[0][64 + row][kc * 8], Wb1 + k2);
                oya0 = *(const uint4*)(Ab0 + k3); oya1 = *(const uint4*)(Ab1 + k3);
                osz0 = *(const uint4*)(Zb0 + k3); osz1 = *(const uint4*)(Zb1 + k3);
            }
            compute_tile(Als[1], Bls[1], acc, wm, wn, mr, quad);
            __syncthreads();
        }
    } else {
        gld16(&Als[0][row][kc * 8], Ab0);
        gld16(&Als[0][64 + row][kc * 8], Ab1);
        gld16(&Bls[0][row][kc * 8], Wb0);
        gld16(&Bls[0][64 + row][kc * 8], Wb1);
        __syncthreads();
        for (int t = 0; t < NT; t += 2) {
            int k1 = (t + 1) * 32, k2 = (t + 2) * 32;
            gld16(&Als[1][row][kc * 8], Ab0 + k1);
            gld16(&Als[1][64 + row][kc * 8], Ab1 + k1);
            gld16(&Bls[1][row][kc * 8], Wb0 + k1);
            gld16(&Bls[1][64 + row][kc * 8], Wb1 + k1);
            compute_tile(Als[0], Bls[0], acc, wm, wn, mr, quad);
            __syncthreads();
            if (t + 2 < NT) {
                gld16(&Als[0][row][kc * 8], Ab0 + k2);
                gld16(&Als[0][64 + row][kc * 8], Ab1 + k2);
                gld16(&Bls[0][row][kc * 8], Wb0 + k2);
                gld16(&Bls[0][64 + row][kc * 8], Wb1 + k2);
            }
            compute_tile(Als[1], Bls[1], acc, wm, wn, mr, quad);
            __syncthreads();
        }
    }

    bool f32m = (MODE == 1) ? (*flag != 0) : false;
#pragma unroll
    for (int r = 0; r < 4; ++r) {
#pragma unroll
        for (int c = 0; c < 4; ++c) {
#pragma unroll
            for (int reg = 0; reg < 4; ++reg) {
                int gm = m0 + wm * 64 + r * 16 + quad * 4 + reg;
                int gn = n0 + wn * 64 + c * 16 + mr;
                float v = acc[r][c][reg];
                if (MODE == 0 || MODE == 5) {
                    C[(size_t)gm * ldc + cofs + gn] = f2b(v);
                } else if (MODE == 2) {
                    if (gn < DTRANK + 2 * DSTATE) Cf[(size_t)gm * 56 + gn] = v;
                } else if (MODE == 4) {  // combined in-proj: xi | silu(z) bf16
                    if (gn < DINNER) {
                        C[(size_t)gm * DINNER + gn] = f2b(v);
                    } else {
                        float sz = v / (1.f + __expf(-v));
                        Cz[(size_t)gm * DINNER + (gn - DINNER)] = f2b(sz);
                    }
                } else {  // MODE 1 gate: g*yf + (1-g)*yb + x  (A == ycat)
                    float g   = 1.f / (1.f + __expf(-(v + gb[gn])));
                    float yfv = b2f(A[(size_t)gm * DINNER + gn]);
                    float ybv = b2f(A[(size_t)gm * DINNER + DMODEL + gn]);
                    size_t gi = xoff + (size_t)gm * DMODEL + gn;
                    float xv  = f32m ? ((const float*)xg)[gi] : b2f(((const bf16*)xg)[gi]);
                    float rr  = g * yfv + (1.f - g) * ybv + xv;
                    if (f32m) ((float*)outg)[gi] = rr;
                    else      ((bf16*)outg)[gi]  = f2b(rr);
                }
            }
        }
    }
}

// ------------------------------------------------------------------
// Depthwise conv + SiLU, bf16. R9: 8 channels/thread, uint4 tap loads
// (was 9 loads per 1 output: 4 scalar-bf16 taps + 4 f32 weights + bias;
// now 4 uint4 taps + 8 float4 weights + 1 uint4 store per 8 outputs).
// All loops fully unrolled -> static indexing (rule #20 safe).
// ------------------------------------------------------------------
__global__ void conv_kernel(const bf16* __restrict__ xi_buf, const float* __restrict__ cw,
                            const float* __restrict__ cb, bf16* __restrict__ xc, int reverse) {
    int g = blockIdx.x * blockDim.x + threadIdx.x;   // one per 8 channels
    int c8 = (g % (DINNER / 8)) * 8;
    int bl = g / (DINNER / 8);
    int l = bl % SEQ;
    int b = bl / SEQ;
    float4 wq[8];
#pragma unroll
    for (int j = 0; j < 8; ++j) wq[j] = *(const float4*)(cw + (c8 + j) * 4);
    float4 cb0 = *(const float4*)(cb + c8);
    float4 cb1 = *(const float4*)(cb + c8 + 4);
    float acc[8] = {cb0.x, cb0.y, cb0.z, cb0.w, cb1.x, cb1.y, cb1.z, cb1.w};

    const bf16* base = xi_buf + (size_t)b * SEQ * DINNER + c8;
#pragma unroll
    for (int k = 0; k < 4; ++k) {
        int ll = reverse ? (l + k) : (l - 3 + k);
        int wk = reverse ? (3 - k) : k;
        if (ll >= 0 && ll < SEQ) {
            uint4 v = *(const uint4*)(base + (size_t)ll * DINNER);
            const bf16* vb = (const bf16*)&v;
#pragma unroll
            for (int j = 0; j < 8; ++j)
                acc[j] += b2f(vb[j]) * ((const float*)&wq[j])[wk];
        }
    }
    uint4 out;
    bf16* ob = (bf16*)&out;
#pragma unroll
    for (int j = 0; j < 8; ++j)
        ob[j] = f2b(acc[j] / (1.f + __expf(-acc[j])));
    *(uint4*)(xc + (size_t)bl * DINNER + c8) = out;
}

// ------------------------------------------------------------------
// dt precompute (R4-verified): weights pinned in VGPRs, HW softplus.
// ------------------------------------------------------------------
__global__ __launch_bounds__(256, 4) void dt_kernel(const float* __restrict__ xp,
                                                    const float* __restrict__ dtwT,
                                                    const float* __restrict__ dtb,
                                                    float* __restrict__ dtf) {
    __shared__ float4 xps[DTR_R][6];   // 24 xp values per token
    int tid = threadIdx.x;
    int c = blockIdx.y * 256 + tid;
    float w[DTRANK];
#pragma unroll
    for (int r = 0; r < DTRANK; ++r) w[r] = dtwT[r * DINNER + c];
#pragma unroll
    for (int r = 0; r < DTRANK; ++r) asm volatile("" : "+v"(w[r]));  // pin in VGPRs
    float bias = dtb[c];

    size_t row0 = (size_t)blockIdx.x * DTR_R;
    for (int i = tid; i < DTR_R * 6; i += 256) {
        int s = i / 6, q = i % 6;
        xps[s][q] = *(const float4*)(xp + (row0 + s) * 56 + q * 4);
    }
    __syncthreads();

    for (int s = 0; s < DTR_R; s += 2) {
        float a0 = bias, a1 = bias;
#pragma unroll
        for (int q = 0; q < 6; ++q) {
            float4 x0 = xps[s][q];
            float4 x1 = xps[s + 1][q];
            a0 += x0.x * w[q * 4 + 0];  a1 += x1.x * w[q * 4 + 0];
            a0 += x0.y * w[q * 4 + 1];  a1 += x1.y * w[q * 4 + 1];
            a0 += x0.z * w[q * 4 + 2];  a1 += x1.z * w[q * 4 + 2];
            a0 += x0.w * w[q * 4 + 3];  a1 += x1.w * w[q * 4 + 3];
        }
        // hardware softplus: max(x,0) + ln2*log2(1 + 2^(-|x|*log2e))
        float e0 = __builtin_amdgcn_exp2f(fabsf(a0) * -1.44269504f);
        float e1 = __builtin_amdgcn_exp2f(fabsf(a1) * -1.44269504f);
        a0 = fmaxf(a0, 0.f) + 0.69314718f * __builtin_amdgcn_logf(1.f + e0);
        a1 = fmaxf(a1, 0.f) + 0.69314718f * __builtin_amdgcn_logf(1.f + e1);
        dtf[(row0 + s) * DINNER + c]     = a0;
        dtf[(row0 + s + 1) * DINNER + c] = a1;
    }
}

// ------------------------------------------------------------------
// Chunked selective scan, pointer-marching (R7-verified; R8's 16-deep
// register prefetch SPILLED to scratch -- WRITE_SIZE 24.6->135MB,
// VALUBusy 20% -- reverted exactly to this known-good form).
// ------------------------------------------------------------------
template <int PHASE>
__global__ void scan_phase(const float* __restrict__ xp, const bf16* __restrict__ xc,
                           const float* __restrict__ dtf, const float* __restrict__ Alog,
                           const float* __restrict__ Dg, float* __restrict__ states,
                           bf16* __restrict__ ydir, int reverse, const int* __restrict__ flag) {
    __shared__ float xps[16][32];
    bool generic = (flag[1] != 0);
    int tid = threadIdx.x;
    int bidx = blockIdx.x;
    int tc  = bidx % TC;
    int cgb = bidx / TC;       // bb*6+cg
    int cg  = cgb % 6;
    int bb  = cgb / 6;
    int c = cg * 128 + tid;

    float Av0 = -__expf(Alog[c * DSTATE]);
    float Av[DSTATE];
    if (generic) {
#pragma unroll
        for (int n = 0; n < DSTATE; ++n) Av[n] = -__expf(Alog[c * DSTATE + n]);
    }
    float Dv = Dg[c];

    float h[DSTATE];
    float Q = 1.f, Pg[DSTATE];
    size_t sbase = (size_t)bidx * 32;
    if (PHASE == 0) {
#pragma unroll
        for (int n = 0; n < DSTATE; ++n) { h[n] = 0.f; Pg[n] = 1.f; }
    } else {
#pragma unroll
        for (int n = 0; n < DSTATE; ++n) h[n] = states[(sbase + n) * 128 + tid];
    }

    const size_t brow = (size_t)bb * SEQ;
    const int t0 = tc * CL;
    const int tr0 = reverse ? (SEQ - 1 - t0) : t0;
    const long dstep = reverse ? -(long)DINNER : (long)DINNER;
    const float* pdt = dtf + (brow + tr0) * DINNER + c;
    const bf16*  pxc = xc  + (brow + tr0) * DINNER + c;
    bf16* pyd = (PHASE == 1) ? (ydir + (brow + tr0) * DINNER + c) : nullptr;

    for (int g0 = 0; g0 < CL; g0 += 16) {
        __syncthreads();
        for (int i = tid; i < 16 * 32; i += 128) {
            int s = i >> 5, r = i & 31;
            int t = t0 + g0 + s;
            int tr = reverse ? (SEQ - 1 - t) : t;
            xps[s][r] = xp[(brow + tr) * 56 + 24 + r];
        }
        __syncthreads();
        for (int s = 0; s < 16; ++s) {
            float dt  = *pdt;  pdt += dstep;
            float xcv = b2f(*pxc);  pxc += dstep;
            float dtx = dt * xcv;
            float accv = 0.f;
            if (!generic) {
                float e1 = __expf(dt * Av0);
                float d = e1;
#pragma unroll
                for (int n = 0; n < DSTATE; ++n) {
                    h[n] = d * h[n] + dtx * xps[s][n];
                    if (PHASE == 1) accv += h[n] * xps[s][16 + n];
                    d *= e1;
                }
                if (PHASE == 0) Q *= e1;
            } else {
#pragma unroll
                for (int n = 0; n < DSTATE; ++n) {
                    float dA = __expf(dt * Av[n]);
                    h[n] = dA * h[n] + dtx * xps[s][n];
                    if (PHASE == 0) Pg[n] *= dA;
                    else accv += h[n] * xps[s][16 + n];
                }
            }
            if (PHASE == 1) {
                *pyd = f2b(accv + xcv * Dv);
                pyd += dstep;
            }
        }
    }
    if (PHASE == 0) {
        if (!generic) {
            float d = Q;
#pragma unroll
            for (int n = 0; n < DSTATE; ++n) { Pg[n] = d; d *= Q; }
        }
#pragma unroll
        for (int n = 0; n < DSTATE; ++n) {
            states[(sbase + n) * 128 + tid]      = Pg[n];
            states[(sbase + 16 + n) * 128 + tid] = h[n];
        }
    }
}

__global__ void scan_stitch(float* __restrict__ states) {
    int tid = threadIdx.x;
    int cgb = blockIdx.x;
    float h[DSTATE];
#pragma unroll
    for (int n = 0; n < DSTATE; ++n) h[n] = 0.f;
    for (int tc = 0; tc < TC; ++tc) {
        size_t base = ((size_t)cgb * TC + tc) * 32;
#pragma unroll
        for (int n = 0; n < DSTATE; ++n) {
            float Pv = states[(base + n) * 128 + tid];
            float ev = states[(base + 16 + n) * 128 + tid];
            states[(base + n) * 128 + tid] = h[n];   // h_in for this chunk
            h[n] = Pv * h[n] + ev;
        }
    }
}

// ------------------------------------------------------------------
extern "C" void kernel_launch(void* const* d_in, const int* in_sizes, int n_in,
                              void* d_out, int out_size, void* d_ws, size_t ws_size,
                              hipStream_t stream) {
    (void)n_in; (void)out_size;
    bool dict_order = (in_sizes[4] < 2048);
    int fbase = dict_order ? 5 : 3;
    int bbase = dict_order ? 14 : 12;
    int gwi = dict_order ? 3 : 21;
    int gbi = dict_order ? 4 : 22;

    auto al = [](size_t b) { return (b + 255) & ~(size_t)255; };
    char* ws = (char*)d_ws;
    size_t off = 0;
    auto alloc = [&](size_t bytes) {
        void* p = ws + off;
        off += al(bytes);
        return p;
    };

    int* flag = (int*)alloc(256);

    CvtF pf{};
    int cf = 0;
    auto addf = [&](int idx, int n) {
        float* d = (float*)alloc((size_t)n * 4);
        pf.src[cf] = d_in[idx]; pf.dst[cf] = d; pf.n[cf] = n; ++cf;
        return d;
    };
    float* ln_gc   = addf(1, DMODEL);
    float* ln_bc   = addf(2, DMODEL);
    float* gate_bc = addf(gbi, DMODEL);
    float* convw_f[2], *convb_f[2], *dtw_f[2], *dtb_f[2], *alog_f[2], *dd_f[2];
    for (int d = 0; d < 2; ++d) {
        int base = d ? bbase : fbase;
        convw_f[d] = addf(base + 1, DINNER * 4);
        convb_f[d] = addf(base + 2, DINNER);
        dtw_f[d]   = addf(base + 4, DINNER * DTRANK);
        dtb_f[d]   = addf(base + 5, DINNER);
        alog_f[d]  = addf(base + 6, DINNER * DSTATE);
        dd_f[d]    = addf(base + 7, DINNER);
    }

    CvtB pb{};
    int cb = 0;
    auto addb = [&](int idx, int n, size_t alloc_n) {
        bf16* d = (bf16*)alloc(alloc_n * 2);
        pb.src[cb] = d_in[idx]; pb.dst[cb] = d; pb.n[cb] = n; ++cb;
        return d;
    };
    bf16* gate_wb = addb(gwi, DMODEL * 2 * DMODEL, (size_t)DMODEL * 2 * DMODEL);
    bf16 *inw_b[2], *xpw_b[2], *outw_b[2];
    for (int d = 0; d < 2; ++d) {
        int base = d ? bbase : fbase;
        inw_b[d]  = addb(base + 0, 2 * DINNER * DMODEL, (size_t)2 * DINNER * DMODEL);
        xpw_b[d]  = addb(base + 3, 56 * DINNER, (size_t)128 * DINNER);  // padded
        outw_b[d] = addb(base + 8, DMODEL * DINNER, (size_t)DMODEL * DINNER);
    }

    // transposed dt weights (f32, [24][768]) for coalesced dt_kernel
    float* dtwT_f[2];
    for (int d = 0; d < 2; ++d)
        dtwT_f[d] = (float*)alloc((size_t)DTRANK * DINNER * 4);

    size_t fixed = off;

    // per-chunk activations (silu(z) stored bf16)
    auto chunk_need = [&](int bc) {
        size_t T = (size_t)bc * SEQ;
        return al(T * DMODEL * 2)                       // xn
             + 2 * al(T * DINNER * 2)                   // xi(/ydir), xc
             + al(T * 56 * 4)                           // xp f32
             + al(T * DINNER * 4)                       // dt f32
             + al(T * DINNER * 2)                       // silu(z) bf16
             + al(T * DINNER * 2)                       // ycat
             + al((size_t)bc * 6 * TC * 32 * 128 * 4);  // scan states
    };
    int Bc = 32;
    while (Bc > 1 && fixed + chunk_need(Bc) > ws_size) Bc >>= 1;
    size_t T = (size_t)Bc * SEQ;
    int nMT = (int)(T / 128);   // M tiles; = 8*Bc, divisible by 8

    bf16*  xn_c   = (bf16*)alloc(T * DMODEL * 2);
    bf16*  xib    = (bf16*)alloc(T * DINNER * 2);
    bf16*  xcb    = (bf16*)alloc(T * DINNER * 2);
    float* xpb    = (float*)alloc(T * 56 * 4);
    float* dtfb   = (float*)alloc(T * DINNER * 4);
    bf16*  zbb    = (bf16*)alloc(T * DINNER * 2);
    bf16*  ycat   = (bf16*)alloc(T * DINNER * 2);
    float* states = (float*)alloc((size_t)Bc * 6 * TC * 32 * 128 * 4);
    bf16*  ydir   = xib;  // alias: xi dead after conv

    hipMemsetAsync(flag, 0, 8, stream);
    for (int d = 0; d < 2; ++d)
        hipMemsetAsync(xpw_b[d], 0, (size_t)128 * DINNER * 2, stream);
    detect_kernel<<<1, 256, 0, stream>>>((const unsigned short*)d_in[0], flag);
    convert_f_kernel<<<dim3(8, 15), 256, 0, stream>>>(pf, flag);
    convert_b_kernel<<<dim3(32, 7), 256, 0, stream>>>(pb, flag);
    struct_check<<<3, 256, 0, stream>>>(alog_f[0], flag);
    struct_check<<<3, 256, 0, stream>>>(alog_f[1], flag);
    for (int d = 0; d < 2; ++d)
        transpose_dtw<<<(DINNER * DTRANK + 255) / 256, 256, 0, stream>>>(dtw_f[d], dtwT_f[d]);

    for (int c0 = 0; c0 < BATCH; c0 += Bc) {
        size_t tok0 = (size_t)c0 * SEQ;

        ln_kernel<<<(unsigned)(T / 4), 256, 0, stream>>>(
            d_in[0], tok0 * DMODEL, ln_gc, ln_bc, xn_c, flag);

        for (int dir = 0; dir < 2; ++dir) {
            // combined in-proj: xi (bf16) + silu(z) (bf16), nNT=12
            gemm_mfma<4><<<nMT * 12, 256, 0, stream>>>(
                xn_c, inw_b[dir], DMODEL, DMODEL, DMODEL, 12,
                xib, DINNER, 0, nullptr, zbb, nullptr,
                nullptr, nullptr, 0, nullptr, flag);
            conv_kernel<<<(unsigned)((T * DINNER) / 2048), 256, 0, stream>>>(
                xib, convw_f[dir], convb_f[dir], xcb, dir);
            // x-proj (56 cols padded to 128), nNT=1
            gemm_mfma<2><<<nMT * 1, 256, 0, stream>>>(
                xcb, xpw_b[dir], DINNER, DINNER, DINNER, 1,
                nullptr, 0, 0, xpb, nullptr, nullptr,
                nullptr, nullptr, 0, nullptr, flag);
            dt_kernel<<<dim3((unsigned)(T / DTR_R), 3), 256, 0, stream>>>(
                xpb, dtwT_f[dir], dtb_f[dir], dtfb);
            // chunked scan
            scan_phase<0><<<Bc * 6 * TC, 128, 0, stream>>>(
                xpb, xcb, dtfb, alog_f[dir], dd_f[dir], states, nullptr, dir, flag);
            scan_stitch<<<Bc * 6, 128, 0, stream>>>(states);
            scan_phase<1><<<Bc * 6 * TC, 128, 0, stream>>>(
                xpb, xcb, dtfb, alog_f[dir], dd_f[dir], states, ydir, dir, flag);
            // out-proj with fused a = ydir * sz; nNT=3
            gemm_mfma<5><<<nMT * 3, 256, 0, stream>>>(
                ydir, outw_b[dir], DINNER, DINNER, DINNER, 3,
                ycat, DINNER, dir * DMODEL, nullptr, nullptr, zbb,
                nullptr, nullptr, 0, nullptr, flag);
        }

        // gate GEMM + combine + residual, nNT=3
        gemm_mfma<1><<<nMT * 3, 256, 0, stream>>>(
            ycat, gate_wb, DINNER, DINNER, DINNER, 3,
            nullptr, 0, 0, nullptr, nullptr, nullptr,
            gate_bc, d_in[0], tok0 * DMODEL, d_out, flag);
    }
}

// Round 11
// 1265.283 us; speedup vs baseline: 1.2666x; 1.0004x over previous
//
#include <hip/hip_runtime.h>
#include <hip/hip_bf16.h>

#define BATCH  32
#define SEQ    1024
#define DMODEL 384
#define DINNER 768
#define DSTATE 16
#define DTRANK 24
#define NTOK   (BATCH * SEQ)
#define TC     32             // time chunks for parallel scan
#define CL     (SEQ / TC)     // 32 steps per chunk
#define DTR_R  32             // tokens per dt block

typedef __hip_bfloat16 bf16;
typedef __attribute__((ext_vector_type(8))) short frag_ab;  // 8 bf16
typedef __attribute__((ext_vector_type(4))) float frag_cd;  // 4 f32

__device__ __forceinline__ float b2f(bf16 v) { return __bfloat162float(v); }
__device__ __forceinline__ bf16  f2b(float v) { return __float2bfloat16(v); }
__device__ __forceinline__ float ldx(const void* p, size_t i, bool f32m) {
    return f32m ? ((const float*)p)[i] : b2f(((const bf16*)p)[i]);
}

// async global->LDS, 16B per lane (wave-uniform LDS base + lane*16)
__device__ __forceinline__ void gld16(void* l, const void* g) {
    __builtin_amdgcn_global_load_lds(
        (const __attribute__((address_space(1))) unsigned int*)g,
        (__attribute__((address_space(3))) unsigned int*)l, 16, 0, 0);
}

// elementwise bf16 product of 8 pairs (f32 math, one rounding)
__device__ __forceinline__ uint4 bmul8(uint4 y, uint4 s) {
    const bf16* yb = (const bf16*)&y;
    const bf16* sb = (const bf16*)&s;
    uint4 r;
    bf16* rb = (bf16*)&r;
#pragma unroll
    for (int j = 0; j < 8; ++j) rb[j] = f2b(b2f(yb[j]) * b2f(sb[j]));
    return r;
}

// ------------------------------------------------------------------
// Input-dtype detection (f32 vs bf16). Verified: inputs are f32.
// ------------------------------------------------------------------
__global__ void detect_kernel(const unsigned short* __restrict__ x, int* flag) {
    int bad = 0;
    for (int i = threadIdx.x; i < 16384; i += 256) {
        int e = (x[i] >> 7) & 0xFF;
        bad |= (e >= 0xE0);
    }
    if (bad) atomicOr(flag, 1);
}

// ------------------------------------------------------------------
// A-structure check: Av[n]/Av[0] == n+1 (A_log = log(1..16) broadcast).
// ------------------------------------------------------------------
__global__ void struct_check(const float* __restrict__ alog, int* flag) {
    int c = blockIdx.x * 256 + threadIdx.x;
    if (c >= DINNER) return;
    float a0 = __expf(alog[c * 16]);
    int bad = 0;
#pragma unroll
    for (int n = 1; n < DSTATE; ++n) {
        float r = __expf(alog[c * 16 + n]) / a0;
        bad |= (fabsf(r - (float)(n + 1)) > 1e-3f * (n + 1));
    }
    if (bad) atomicOr(flag + 1, 1);
}

// ------------------------------------------------------------------
// Weight conversion: small params -> f32, GEMM weights -> bf16.
// ------------------------------------------------------------------
struct CvtF { const void* src[15]; float* dst[15]; int n[15]; };
struct CvtB { const void* src[7];  bf16*  dst[7];  int n[7];  };

__global__ void convert_f_kernel(CvtF p, const int* __restrict__ flag) {
    bool f32m = (*flag != 0);
    int y = blockIdx.y;
    const void* s = p.src[y];
    float* d = p.dst[y];
    int n = p.n[y];
    for (int i = blockIdx.x * 256 + threadIdx.x; i < n; i += gridDim.x * 256)
        d[i] = ldx(s, i, f32m);
}
__global__ void convert_b_kernel(CvtB p, const int* __restrict__ flag) {
    bool f32m = (*flag != 0);
    int y = blockIdx.y;
    const void* s = p.src[y];
    bf16* d = p.dst[y];
    int n = p.n[y];
    for (int i = blockIdx.x * 256 + threadIdx.x; i < n; i += gridDim.x * 256)
        d[i] = f2b(ldx(s, i, f32m));
}

// ------------------------------------------------------------------
// dtw transpose: [768][24] f32 -> [24][768] f32 (coalesced dt_kernel).
// ------------------------------------------------------------------
__global__ void transpose_dtw(const float* __restrict__ w, float* __restrict__ wt) {
    int i = blockIdx.x * 256 + threadIdx.x;
    if (i >= DINNER * DTRANK) return;
    int c = i / DTRANK, r = i % DTRANK;
    wt[r * DINNER + c] = w[i];
}

// ------------------------------------------------------------------
// LayerNorm: one wave per row of 384; writes bf16 xn.
// ------------------------------------------------------------------
__global__ void ln_kernel(const void* __restrict__ x, size_t xoff,
                          const float* __restrict__ gamma, const float* __restrict__ beta,
                          bf16* __restrict__ xn, const int* __restrict__ flag) {
    bool f32m = (*flag != 0);
    int wave = threadIdx.x >> 6;
    int lane = threadIdx.x & 63;
    int row  = blockIdx.x * 4 + wave;
    size_t base = xoff + (size_t)row * DMODEL;
    float v[6];
    float s = 0.f, s2 = 0.f;
#pragma unroll
    for (int i = 0; i < 6; ++i) {
        v[i] = ldx(x, base + lane + i * 64, f32m);
        s += v[i];
        s2 += v[i] * v[i];
    }
#pragma unroll
    for (int off = 32; off >= 1; off >>= 1) {
        s  += __shfl_down(s, off, 64);
        s2 += __shfl_down(s2, off, 64);
    }
    s  = __shfl(s, 0, 64);
    s2 = __shfl(s2, 0, 64);
    float mu   = s / DMODEL;
    float var  = s2 / DMODEL - mu * mu;
    float rstd = rsqrtf(var + 1e-5f);
    bf16* xnr = xn + (size_t)row * DMODEL;
#pragma unroll
    for (int i = 0; i < 6; ++i)
        xnr[lane + i * 64] = f2b((v[i] - mu) * rstd * gamma[lane + i * 64] + beta[lane + i * 64]);
}

// MFMA tile compute: 8 ds_read_b128 + 16 MFMA on one LDS buffer
__device__ __forceinline__ void compute_tile(const bf16 (*Al)[32], const bf16 (*Bl)[32],
                                             frag_cd acc[4][4], int wm, int wn,
                                             int mr, int quad) {
    frag_ab af[4], bfr[4];
#pragma unroll
    for (int r = 0; r < 4; ++r)
        af[r] = *(const frag_ab*)&Al[wm * 64 + r * 16 + mr][quad * 8];
#pragma unroll
    for (int c = 0; c < 4; ++c)
        bfr[c] = *(const frag_ab*)&Bl[wn * 64 + c * 16 + mr][quad * 8];
#pragma unroll
    for (int r = 0; r < 4; ++r)
#pragma unroll
        for (int c = 0; c < 4; ++c)
            acc[r][c] = __builtin_amdgcn_mfma_f32_16x16x32_bf16(af[r], bfr[c], acc[r][c], 0, 0, 0);
}

// ------------------------------------------------------------------
// MFMA bf16 GEMM, 128x128 tile, BK=32, 256 threads (2x2 waves of 64x64).
// C[M,N] = A[M,K] @ W[N,K]^T.  Double-buffered gld16 pipeline (R6).
// R7: XCD-aware 1-D grid decode (verified: FETCH 62->36MB on gate).
// MODE 1: gate epilogue -> d_out.   MODE 2: f32 store, 56 valid cols.
// MODE 4: in-proj combined: xi bf16 | silu(z) bf16.
// MODE 5: out-proj, A-staging multiplies a = ydir * sz (bf16).
// ------------------------------------------------------------------
template <int MODE>
__global__ __launch_bounds__(256) void gemm_mfma(
    const bf16* __restrict__ A, const bf16* __restrict__ W,
    int K, int lda, int ldw, int nNT,
    bf16* __restrict__ C, int ldc, int cofs,
    float* __restrict__ Cf, bf16* __restrict__ Cz, const bf16* __restrict__ Sz,
    const float* __restrict__ gb, const void* __restrict__ xg, size_t xoff,
    void* __restrict__ outg, const int* __restrict__ flag) {
    __shared__ bf16 Als[2][128][32];
    __shared__ bf16 Bls[2][128][32];
    int tid = threadIdx.x;
    int lane = tid & 63;
    int w = tid >> 6;
    int wm = w & 1, wn = w >> 1;
    // XCD-aware decode (see header comment)
    int wgid = blockIdx.x;
    int mt_lo = wgid & 7;
    int rr_ = wgid >> 3;
    int nt = rr_ % nNT;
    int mt = (rr_ / nNT) * 8 + mt_lo;
    int m0 = mt * 128, n0 = nt * 128;
    int row = tid >> 2, kc = tid & 3;
    int mr = lane & 15, quad = lane >> 4;

    const bf16* Ab0 = A + (size_t)(m0 + row) * lda + kc * 8;
    const bf16* Ab1 = A + (size_t)(m0 + 64 + row) * lda + kc * 8;
    const bf16* Wb0 = W + (size_t)(n0 + row) * ldw + kc * 8;
    const bf16* Wb1 = W + (size_t)(n0 + 64 + row) * ldw + kc * 8;
    const bf16* Zb0 = (MODE == 5) ? (Sz + (size_t)(m0 + row) * DINNER + kc * 8) : nullptr;
    const bf16* Zb1 = (MODE == 5) ? (Sz + (size_t)(m0 + 64 + row) * DINNER + kc * 8) : nullptr;

    frag_cd acc[4][4] = {};
    const int NT = K / 32;   // always even (12 or 24)

    if (MODE == 5) {
        uint4 eya0, eya1, esz0, esz1;   // even-tile regs
        uint4 oya0, oya1, osz0, osz1;   // odd-tile regs
        eya0 = *(const uint4*)(Ab0);      eya1 = *(const uint4*)(Ab1);
        esz0 = *(const uint4*)(Zb0);      esz1 = *(const uint4*)(Zb1);
        oya0 = *(const uint4*)(Ab0 + 32); oya1 = *(const uint4*)(Ab1 + 32);
        osz0 = *(const uint4*)(Zb0 + 32); osz1 = *(const uint4*)(Zb1 + 32);
        // prologue: tile 0 into buf 0
        *(uint4*)&Als[0][row][kc * 8]      = bmul8(eya0, esz0);
        *(uint4*)&Als[0][64 + row][kc * 8] = bmul8(eya1, esz1);
        gld16(&Bls[0][row][kc * 8], Wb0);
        gld16(&Bls[0][64 + row][kc * 8], Wb1);
        __syncthreads();
        for (int t = 0; t < NT; t += 2) {
            int k1 = (t + 1) * 32, k2 = (t + 2) * 32, k3 = (t + 3) * 32;
            *(uint4*)&Als[1][row][kc * 8]      = bmul8(oya0, osz0);
            *(uint4*)&Als[1][64 + row][kc * 8] = bmul8(oya1, osz1);
            gld16(&Bls[1][row][kc * 8], Wb0 + k1);
            gld16(&Bls[1][64 + row][kc * 8], Wb1 + k1);
            if (t + 2 < NT) {
                eya0 = *(const uint4*)(Ab0 + k2); eya1 = *(const uint4*)(Ab1 + k2);
                esz0 = *(const uint4*)(Zb0 + k2); esz1 = *(const uint4*)(Zb1 + k2);
            }
            compute_tile(Als[0], Bls[0], acc, wm, wn, mr, quad);
            __syncthreads();
            if (t + 2 < NT) {
                *(uint4*)&Als[0][row][kc * 8]      = bmul8(eya0, esz0);
                *(uint4*)&Als[0][64 + row][kc * 8] = bmul8(eya1, esz1);
                gld16(&Bls[0][row][kc * 8], Wb0 + k2);
                gld16(&Bls[0][64 + row][kc * 8], Wb1 + k2);
                oya0 = *(const uint4*)(Ab0 + k3); oya1 = *(const uint4*)(Ab1 + k3);
                osz0 = *(const uint4*)(Zb0 + k3); osz1 = *(const uint4*)(Zb1 + k3);
            }
            compute_tile(Als[1], Bls[1], acc, wm, wn, mr, quad);
            __syncthreads();
        }
    } else {
        gld16(&Als[0][row][kc * 8], Ab0);
        gld16(&Als[0][64 + row][kc * 8], Ab1);
        gld16(&Bls[0][row][kc * 8], Wb0);
        gld16(&Bls[0][64 + row][kc * 8], Wb1);
        __syncthreads();
        for (int t = 0; t < NT; t += 2) {
            int k1 = (t + 1) * 32, k2 = (t + 2) * 32;
            gld16(&Als[1][row][kc * 8], Ab0 + k1);
            gld16(&Als[1][64 + row][kc * 8], Ab1 + k1);
            gld16(&Bls[1][row][kc * 8], Wb0 + k1);
            gld16(&Bls[1][64 + row][kc * 8], Wb1 + k1);
            compute_tile(Als[0], Bls[0], acc, wm, wn, mr, quad);
            __syncthreads();
            if (t + 2 < NT) {
                gld16(&Als[0][row][kc * 8], Ab0 + k2);
                gld16(&Als[0][64 + row][kc * 8], Ab1 + k2);
                gld16(&Bls[0][row][kc * 8], Wb0 + k2);
                gld16(&Bls[0][64 + row][kc * 8], Wb1 + k2);
            }
            compute_tile(Als[1], Bls[1], acc, wm, wn, mr, quad);
            __syncthreads();
        }
    }

    bool f32m = (MODE == 1) ? (*flag != 0) : false;
#pragma unroll
    for (int r = 0; r < 4; ++r) {
#pragma unroll
        for (int c = 0; c < 4; ++c) {
#pragma unroll
            for (int reg = 0; reg < 4; ++reg) {
                int gm = m0 + wm * 64 + r * 16 + quad * 4 + reg;
                int gn = n0 + wn * 64 + c * 16 + mr;
                float v = acc[r][c][reg];
                if (MODE == 0 || MODE == 5) {
                    C[(size_t)gm * ldc + cofs + gn] = f2b(v);
                } else if (MODE == 2) {
                    if (gn < DTRANK + 2 * DSTATE) Cf[(size_t)gm * 56 + gn] = v;
                } else if (MODE == 4) {  // combined in-proj: xi | silu(z) bf16
                    if (gn < DINNER) {
                        C[(size_t)gm * DINNER + gn] = f2b(v);
                    } else {
                        float sz = v / (1.f + __expf(-v));
                        Cz[(size_t)gm * DINNER + (gn - DINNER)] = f2b(sz);
                    }
                } else {  // MODE 1 gate: g*yf + (1-g)*yb + x  (A == ycat)
                    float g   = 1.f / (1.f + __expf(-(v + gb[gn])));
                    float yfv = b2f(A[(size_t)gm * DINNER + gn]);
                    float ybv = b2f(A[(size_t)gm * DINNER + DMODEL + gn]);
                    size_t gi = xoff + (size_t)gm * DMODEL + gn;
                    float xv  = f32m ? ((const float*)xg)[gi] : b2f(((const bf16*)xg)[gi]);
                    float rr  = g * yfv + (1.f - g) * ybv + xv;
                    if (f32m) ((float*)outg)[gi] = rr;
                    else      ((bf16*)outg)[gi]  = f2b(rr);
                }
            }
        }
    }
}

// ------------------------------------------------------------------
// Depthwise conv + SiLU, bf16. R9-verified: 8 channels/thread, uint4.
// ------------------------------------------------------------------
__global__ void conv_kernel(const bf16* __restrict__ xi_buf, const float* __restrict__ cw,
                            const float* __restrict__ cb, bf16* __restrict__ xc, int reverse) {
    int g = blockIdx.x * blockDim.x + threadIdx.x;   // one per 8 channels
    int c8 = (g % (DINNER / 8)) * 8;
    int bl = g / (DINNER / 8);
    int l = bl % SEQ;
    int b = bl / SEQ;
    float4 wq[8];
#pragma unroll
    for (int j = 0; j < 8; ++j) wq[j] = *(const float4*)(cw + (c8 + j) * 4);
    float4 cb0 = *(const float4*)(cb + c8);
    float4 cb1 = *(const float4*)(cb + c8 + 4);
    float acc[8] = {cb0.x, cb0.y, cb0.z, cb0.w, cb1.x, cb1.y, cb1.z, cb1.w};

    const bf16* base = xi_buf + (size_t)b * SEQ * DINNER + c8;
#pragma unroll
    for (int k = 0; k < 4; ++k) {
        int ll = reverse ? (l + k) : (l - 3 + k);
        int wk = reverse ? (3 - k) : k;
        if (ll >= 0 && ll < SEQ) {
            uint4 v = *(const uint4*)(base + (size_t)ll * DINNER);
            const bf16* vb = (const bf16*)&v;
#pragma unroll
            for (int j = 0; j < 8; ++j)
                acc[j] += b2f(vb[j]) * ((const float*)&wq[j])[wk];
        }
    }
    uint4 out;
    bf16* ob = (bf16*)&out;
#pragma unroll
    for (int j = 0; j < 8; ++j)
        ob[j] = f2b(acc[j] / (1.f + __expf(-acc[j])));
    *(uint4*)(xc + (size_t)bl * DINNER + c8) = out;
}

// ------------------------------------------------------------------
// dt precompute (R4-verified): weights pinned in VGPRs, HW softplus.
// ------------------------------------------------------------------
__global__ __launch_bounds__(256, 4) void dt_kernel(const float* __restrict__ xp,
                                                    const float* __restrict__ dtwT,
                                                    const float* __restrict__ dtb,
                                                    float* __restrict__ dtf) {
    __shared__ float4 xps[DTR_R][6];   // 24 xp values per token
    int tid = threadIdx.x;
    int c = blockIdx.y * 256 + tid;
    float w[DTRANK];
#pragma unroll
    for (int r = 0; r < DTRANK; ++r) w[r] = dtwT[r * DINNER + c];
#pragma unroll
    for (int r = 0; r < DTRANK; ++r) asm volatile("" : "+v"(w[r]));  // pin in VGPRs
    float bias = dtb[c];

    size_t row0 = (size_t)blockIdx.x * DTR_R;
    for (int i = tid; i < DTR_R * 6; i += 256) {
        int s = i / 6, q = i % 6;
        xps[s][q] = *(const float4*)(xp + (row0 + s) * 56 + q * 4);
    }
    __syncthreads();

    for (int s = 0; s < DTR_R; s += 2) {
        float a0 = bias, a1 = bias;
#pragma unroll
        for (int q = 0; q < 6; ++q) {
            float4 x0 = xps[s][q];
            float4 x1 = xps[s + 1][q];
            a0 += x0.x * w[q * 4 + 0];  a1 += x1.x * w[q * 4 + 0];
            a0 += x0.y * w[q * 4 + 1];  a1 += x1.y * w[q * 4 + 1];
            a0 += x0.z * w[q * 4 + 2];  a1 += x1.z * w[q * 4 + 2];
            a0 += x0.w * w[q * 4 + 3];  a1 += x1.w * w[q * 4 + 3];
        }
        // hardware softplus: max(x,0) + ln2*log2(1 + 2^(-|x|*log2e))
        float e0 = __builtin_amdgcn_exp2f(fabsf(a0) * -1.44269504f);
        float e1 = __builtin_amdgcn_exp2f(fabsf(a1) * -1.44269504f);
        a0 = fmaxf(a0, 0.f) + 0.69314718f * __builtin_amdgcn_logf(1.f + e0);
        a1 = fmaxf(a1, 0.f) + 0.69314718f * __builtin_amdgcn_logf(1.f + e1);
        dtf[(row0 + s) * DINNER + c]     = a0;
        dtf[(row0 + s + 1) * DINNER + c] = a1;
    }
}

// ------------------------------------------------------------------
// Chunked selective scan. R10: state-split across lane halves.
// Lanes l and l^32 share one channel; each owns 8 of 16 states.
// Per-thread work halves (R9 profile: VALUBusy 61%, 39% stall, 16-deep
// d-chain); block count doubles (6144 -> full thread occupancy);
// phase-1 combine via one __shfl_xor(accv,32). dt/xc loads duplicate
// across halves at identical addresses (one segment serves both).
// States layout: 32 slots x 64 channels per block (same total bytes).
// ------------------------------------------------------------------
template <int PHASE>
__global__ __launch_bounds__(128) void scan_phase(
        const float* __restrict__ xp, const bf16* __restrict__ xc,
        const float* __restrict__ dtf, const float* __restrict__ Alog,
        const float* __restrict__ Dg, float* __restrict__ states,
        bf16* __restrict__ ydir, int reverse, const int* __restrict__ flag) {
    __shared__ float xps[16][32];
    bool generic = (flag[1] != 0);
    int tid = threadIdx.x;
    int bidx = blockIdx.x;
    int tc  = bidx % TC;
    int cgb = bidx / TC;       // bb*12 + cg  (12 groups of 64 channels)
    int cg  = cgb % 12;
    int bb  = cgb / 12;
    int wave = tid >> 6;
    int lane = tid & 63;
    int half = lane >> 5;      // 0: states 0..7, 1: states 8..15
    int lch  = lane & 31;
    int wch  = wave * 32 + lch;    // channel within block, 0..63
    int c  = cg * 64 + wch;
    int ns = half * 8;

    float Av0 = -__expf(Alog[c * DSTATE]);
    float Av[8];
    if (generic) {
#pragma unroll
        for (int j = 0; j < 8; ++j) Av[j] = -__expf(Alog[c * DSTATE + ns + j]);
    }
    float Dv = Dg[c];

    float h[8];
    float Q = 1.f, Pg[8];
    size_t sbase = (size_t)bidx * 32;
    if (PHASE == 0) {
#pragma unroll
        for (int j = 0; j < 8; ++j) { h[j] = 0.f; Pg[j] = 1.f; }
    } else {
#pragma unroll
        for (int j = 0; j < 8; ++j) h[j] = states[(sbase + ns + j) * 64 + wch];
    }

    const size_t brow = (size_t)bb * SEQ;
    const int t0 = tc * CL;
    const int tr0 = reverse ? (SEQ - 1 - t0) : t0;
    const long dstep = reverse ? -(long)DINNER : (long)DINNER;
    const float* pdt = dtf + (brow + tr0) * DINNER + c;
    const bf16*  pxc = xc  + (brow + tr0) * DINNER + c;
    bf16* pyd = (PHASE == 1) ? (ydir + (brow + tr0) * DINNER + c) : nullptr;

    for (int g0 = 0; g0 < CL; g0 += 16) {
        __syncthreads();
        for (int i = tid; i < 16 * 32; i += 128) {
            int s = i >> 5, r = i & 31;
            int t = t0 + g0 + s;
            int tr = reverse ? (SEQ - 1 - t) : t;
            xps[s][r] = xp[(brow + tr) * 56 + 24 + r];
        }
        __syncthreads();
        for (int s = 0; s < 16; ++s) {
            float dt  = *pdt;  pdt += dstep;
            float xcv = b2f(*pxc);  pxc += dstep;
            float dtx = dt * xcv;
            float accv = 0.f;
            if (!generic) {
                float e1 = __expf(dt * Av0);
                float d;
                if (half) {   // start at e1^9 via 3 squarings + 1 mul
                    float e2 = e1 * e1, e4 = e2 * e2, e8 = e4 * e4;
                    d = e8 * e1;
                } else {
                    d = e1;
                }
#pragma unroll
                for (int j = 0; j < 8; ++j) {
                    h[j] = d * h[j] + dtx * xps[s][ns + j];
                    if (PHASE == 1) accv += h[j] * xps[s][16 + ns + j];
                    d *= e1;
                }
                if (PHASE == 0) Q *= e1;
            } else {
#pragma unroll
                for (int j = 0; j < 8; ++j) {
                    float dA = __expf(dt * Av[j]);
                    h[j] = dA * h[j] + dtx * xps[s][ns + j];
                    if (PHASE == 0) Pg[j] *= dA;
                    else accv += h[j] * xps[s][16 + ns + j];
                }
            }
            if (PHASE == 1) {
                accv += __shfl_xor(accv, 32, 64);
                if (!half) *pyd = f2b(accv + xcv * Dv);
                pyd += dstep;
            }
        }
    }
    if (PHASE == 0) {
        if (!generic) {
            float d;
            if (half) {
                float q2 = Q * Q, q4 = q2 * q2, q8 = q4 * q4;
                d = q8 * Q;
            } else {
                d = Q;
            }
#pragma unroll
            for (int j = 0; j < 8; ++j) { Pg[j] = d; d *= Q; }
        }
#pragma unroll
        for (int j = 0; j < 8; ++j) {
            states[(sbase + ns + j) * 64 + wch]      = Pg[j];
            states[(sbase + 16 + ns + j) * 64 + wch] = h[j];
        }
    }
}

__global__ void scan_stitch(float* __restrict__ states) {
    int tid = threadIdx.x;      // 128: 64 channels x 2 state-halves
    int cgb = blockIdx.x;       // Bc*12
    int wch = tid & 63;
    int ns  = (tid >> 6) * 8;
    float h[8];
#pragma unroll
    for (int j = 0; j < 8; ++j) h[j] = 0.f;
    for (int tc = 0; tc < TC; ++tc) {
        size_t base = ((size_t)cgb * TC + tc) * 32;
#pragma unroll
        for (int j = 0; j < 8; ++j) {
            float Pv = states[(base + ns + j) * 64 + wch];
            float ev = states[(base + 16 + ns + j) * 64 + wch];
            states[(base + ns + j) * 64 + wch] = h[j];   // h_in for this chunk
            h[j] = Pv * h[j] + ev;
        }
    }
}

// ------------------------------------------------------------------
extern "C" void kernel_launch(void* const* d_in, const int* in_sizes, int n_in,
                              void* d_out, int out_size, void* d_ws, size_t ws_size,
                              hipStream_t stream) {
    (void)n_in; (void)out_size;
    bool dict_order = (in_sizes[4] < 2048);
    int fbase = dict_order ? 5 : 3;
    int bbase = dict_order ? 14 : 12;
    int gwi = dict_order ? 3 : 21;
    int gbi = dict_order ? 4 : 22;

    auto al = [](size_t b) { return (b + 255) & ~(size_t)255; };
    char* ws = (char*)d_ws;
    size_t off = 0;
    auto alloc = [&](size_t bytes) {
        void* p = ws + off;
        off += al(bytes);
        return p;
    };

    int* flag = (int*)alloc(256);

    CvtF pf{};
    int cf = 0;
    auto addf = [&](int idx, int n) {
        float* d = (float*)alloc((size_t)n * 4);
        pf.src[cf] = d_in[idx]; pf.dst[cf] = d; pf.n[cf] = n; ++cf;
        return d;
    };
    float* ln_gc   = addf(1, DMODEL);
    float* ln_bc   = addf(2, DMODEL);
    float* gate_bc = addf(gbi, DMODEL);
    float* convw_f[2], *convb_f[2], *dtw_f[2], *dtb_f[2], *alog_f[2], *dd_f[2];
    for (int d = 0; d < 2; ++d) {
        int base = d ? bbase : fbase;
        convw_f[d] = addf(base + 1, DINNER * 4);
        convb_f[d] = addf(base + 2, DINNER);
        dtw_f[d]   = addf(base + 4, DINNER * DTRANK);
        dtb_f[d]   = addf(base + 5, DINNER);
        alog_f[d]  = addf(base + 6, DINNER * DSTATE);
        dd_f[d]    = addf(base + 7, DINNER);
    }

    CvtB pb{};
    int cb = 0;
    auto addb = [&](int idx, int n, size_t alloc_n) {
        bf16* d = (bf16*)alloc(alloc_n * 2);
        pb.src[cb] = d_in[idx]; pb.dst[cb] = d; pb.n[cb] = n; ++cb;
        return d;
    };
    bf16* gate_wb = addb(gwi, DMODEL * 2 * DMODEL, (size_t)DMODEL * 2 * DMODEL);
    bf16 *inw_b[2], *xpw_b[2], *outw_b[2];
    for (int d = 0; d < 2; ++d) {
        int base = d ? bbase : fbase;
        inw_b[d]  = addb(base + 0, 2 * DINNER * DMODEL, (size_t)2 * DINNER * DMODEL);
        xpw_b[d]  = addb(base + 3, 56 * DINNER, (size_t)128 * DINNER);  // padded
        outw_b[d] = addb(base + 8, DMODEL * DINNER, (size_t)DMODEL * DINNER);
    }

    // transposed dt weights (f32, [24][768]) for coalesced dt_kernel
    float* dtwT_f[2];
    for (int d = 0; d < 2; ++d)
        dtwT_f[d] = (float*)alloc((size_t)DTRANK * DINNER * 4);

    size_t fixed = off;

    // per-chunk activations (silu(z) stored bf16)
    auto chunk_need = [&](int bc) {
        size_t T = (size_t)bc * SEQ;
        return al(T * DMODEL * 2)                       // xn
             + 2 * al(T * DINNER * 2)                   // xi(/ydir), xc
             + al(T * 56 * 4)                           // xp f32
             + al(T * DINNER * 4)                       // dt f32
             + al(T * DINNER * 2)                       // silu(z) bf16
             + al(T * DINNER * 2)                       // ycat
             + al((size_t)bc * 12 * TC * 32 * 64 * 4);  // scan states
    };
    int Bc = 32;
    while (Bc > 1 && fixed + chunk_need(Bc) > ws_size) Bc >>= 1;
    size_t T = (size_t)Bc * SEQ;
    int nMT = (int)(T / 128);   // M tiles; = 8*Bc, divisible by 8

    bf16*  xn_c   = (bf16*)alloc(T * DMODEL * 2);
    bf16*  xib    = (bf16*)alloc(T * DINNER * 2);
    bf16*  xcb    = (bf16*)alloc(T * DINNER * 2);
    float* xpb    = (float*)alloc(T * 56 * 4);
    float* dtfb   = (float*)alloc(T * DINNER * 4);
    bf16*  zbb    = (bf16*)alloc(T * DINNER * 2);
    bf16*  ycat   = (bf16*)alloc(T * DINNER * 2);
    float* states = (float*)alloc((size_t)Bc * 12 * TC * 32 * 64 * 4);
    bf16*  ydir   = xib;  // alias: xi dead after conv

    hipMemsetAsync(flag, 0, 8, stream);
    for (int d = 0; d < 2; ++d)
        hipMemsetAsync(xpw_b[d], 0, (size_t)128 * DINNER * 2, stream);
    detect_kernel<<<1, 256, 0, stream>>>((const unsigned short*)d_in[0], flag);
    convert_f_kernel<<<dim3(8, 15), 256, 0, stream>>>(pf, flag);
    convert_b_kernel<<<dim3(32, 7), 256, 0, stream>>>(pb, flag);
    struct_check<<<3, 256, 0, stream>>>(alog_f[0], flag);
    struct_check<<<3, 256, 0, stream>>>(alog_f[1], flag);
    for (int d = 0; d < 2; ++d)
        transpose_dtw<<<(DINNER * DTRANK + 255) / 256, 256, 0, stream>>>(dtw_f[d], dtwT_f[d]);

    for (int c0 = 0; c0 < BATCH; c0 += Bc) {
        size_t tok0 = (size_t)c0 * SEQ;

        ln_kernel<<<(unsigned)(T / 4), 256, 0, stream>>>(
            d_in[0], tok0 * DMODEL, ln_gc, ln_bc, xn_c, flag);

        for (int dir = 0; dir < 2; ++dir) {
            // combined in-proj: xi (bf16) + silu(z) (bf16), nNT=12
            gemm_mfma<4><<<nMT * 12, 256, 0, stream>>>(
                xn_c, inw_b[dir], DMODEL, DMODEL, DMODEL, 12,
                xib, DINNER, 0, nullptr, zbb, nullptr,
                nullptr, nullptr, 0, nullptr, flag);
            conv_kernel<<<(unsigned)((T * DINNER) / 2048), 256, 0, stream>>>(
                xib, convw_f[dir], convb_f[dir], xcb, dir);
            // x-proj (56 cols padded to 128), nNT=1
            gemm_mfma<2><<<nMT * 1, 256, 0, stream>>>(
                xcb, xpw_b[dir], DINNER, DINNER, DINNER, 1,
                nullptr, 0, 0, xpb, nullptr, nullptr,
                nullptr, nullptr, 0, nullptr, flag);
            dt_kernel<<<dim3((unsigned)(T / DTR_R), 3), 256, 0, stream>>>(
                xpb, dtwT_f[dir], dtb_f[dir], dtfb);
            // chunked scan (state-split: 12 groups of 64 channels)
            scan_phase<0><<<Bc * 12 * TC, 128, 0, stream>>>(
                xpb, xcb, dtfb, alog_f[dir], dd_f[dir], states, nullptr, dir, flag);
            scan_stitch<<<Bc * 12, 128, 0, stream>>>(states);
            scan_phase<1><<<Bc * 12 * TC, 128, 0, stream>>>(
                xpb, xcb, dtfb, alog_f[dir], dd_f[dir], states, ydir, dir, flag);
            // out-proj with fused a = ydir * sz; nNT=3
            gemm_mfma<5><<<nMT * 3, 256, 0, stream>>>(
                ydir, outw_b[dir], DINNER, DINNER, DINNER, 3,
                ycat, DINNER, dir * DMODEL, nullptr, nullptr, zbb,
                nullptr, nullptr, 0, nullptr, flag);
        }

        // gate GEMM + combine + residual, nNT=3
        gemm_mfma<1><<<nMT * 3, 256, 0, stream>>>(
            ycat, gate_wb, DINNER, DINNER, DINNER, 3,
            nullptr, 0, 0, nullptr, nullptr, nullptr,
            gate_bc, d_in[0], tok0 * DMODEL, d_out, flag);
    }
}

// Round 12
// 1247.297 us; speedup vs baseline: 1.2849x; 1.0144x over previous
//
#include <hip/hip_runtime.h>
#include <hip/hip_bf16.h>

#define BATCH  32
#define SEQ    1024
#define DMODEL 384
#define DINNER 768
#define DSTATE 16
#define DTRANK 24
#define NTOK   (BATCH * SEQ)
#define TC     32             // time chunks for parallel scan
#define CL     (SEQ / TC)     // 32 steps per chunk
#define DTR_R  32             // tokens per dt block

typedef __hip_bfloat16 bf16;
typedef __attribute__((ext_vector_type(8))) short frag_ab;  // 8 bf16
typedef __attribute__((ext_vector_type(4))) float frag_cd;  // 4 f32

__device__ __forceinline__ float b2f(bf16 v) { return __bfloat162float(v); }
__device__ __forceinline__ bf16  f2b(float v) { return __float2bfloat16(v); }
__device__ __forceinline__ float ldx(const void* p, size_t i, bool f32m) {
    return f32m ? ((const float*)p)[i] : b2f(((const bf16*)p)[i]);
}

// async global->LDS, 16B per lane (wave-uniform LDS base + lane*16)
__device__ __forceinline__ void gld16(void* l, const void* g) {
    __builtin_amdgcn_global_load_lds(
        (const __attribute__((address_space(1))) unsigned int*)g,
        (__attribute__((address_space(3))) unsigned int*)l, 16, 0, 0);
}

// elementwise bf16 product of 8 pairs (f32 math, one rounding)
__device__ __forceinline__ uint4 bmul8(uint4 y, uint4 s) {
    const bf16* yb = (const bf16*)&y;
    const bf16* sb = (const bf16*)&s;
    uint4 r;
    bf16* rb = (bf16*)&r;
#pragma unroll
    for (int j = 0; j < 8; ++j) rb[j] = f2b(b2f(yb[j]) * b2f(sb[j]));
    return r;
}

// ------------------------------------------------------------------
// Input-dtype detection (f32 vs bf16). Verified: inputs are f32.
// ------------------------------------------------------------------
__global__ void detect_kernel(const unsigned short* __restrict__ x, int* flag) {
    int bad = 0;
    for (int i = threadIdx.x; i < 16384; i += 256) {
        int e = (x[i] >> 7) & 0xFF;
        bad |= (e >= 0xE0);
    }
    if (bad) atomicOr(flag, 1);
}

// ------------------------------------------------------------------
// A-structure check: Av[n]/Av[0] == n+1 (A_log = log(1..16) broadcast).
// ------------------------------------------------------------------
__global__ void struct_check(const float* __restrict__ alog, int* flag) {
    int c = blockIdx.x * 256 + threadIdx.x;
    if (c >= DINNER) return;
    float a0 = __expf(alog[c * 16]);
    int bad = 0;
#pragma unroll
    for (int n = 1; n < DSTATE; ++n) {
        float r = __expf(alog[c * 16 + n]) / a0;
        bad |= (fabsf(r - (float)(n + 1)) > 1e-3f * (n + 1));
    }
    if (bad) atomicOr(flag + 1, 1);
}

// ------------------------------------------------------------------
// Weight conversion: small params -> f32, GEMM weights -> bf16.
// ------------------------------------------------------------------
struct CvtF { const void* src[15]; float* dst[15]; int n[15]; };
struct CvtB { const void* src[7];  bf16*  dst[7];  int n[7];  };

__global__ void convert_f_kernel(CvtF p, const int* __restrict__ flag) {
    bool f32m = (*flag != 0);
    int y = blockIdx.y;
    const void* s = p.src[y];
    float* d = p.dst[y];
    int n = p.n[y];
    for (int i = blockIdx.x * 256 + threadIdx.x; i < n; i += gridDim.x * 256)
        d[i] = ldx(s, i, f32m);
}
__global__ void convert_b_kernel(CvtB p, const int* __restrict__ flag) {
    bool f32m = (*flag != 0);
    int y = blockIdx.y;
    const void* s = p.src[y];
    bf16* d = p.dst[y];
    int n = p.n[y];
    for (int i = blockIdx.x * 256 + threadIdx.x; i < n; i += gridDim.x * 256)
        d[i] = f2b(ldx(s, i, f32m));
}

// ------------------------------------------------------------------
// dtw transpose: [768][24] f32 -> [24][768] f32 (coalesced dt_kernel).
// ------------------------------------------------------------------
__global__ void transpose_dtw(const float* __restrict__ w, float* __restrict__ wt) {
    int i = blockIdx.x * 256 + threadIdx.x;
    if (i >= DINNER * DTRANK) return;
    int c = i / DTRANK, r = i % DTRANK;
    wt[r * DINNER + c] = w[i];
}

// ------------------------------------------------------------------
// LayerNorm: one wave per row of 384; writes bf16 xn.
// ------------------------------------------------------------------
__global__ void ln_kernel(const void* __restrict__ x, size_t xoff,
                          const float* __restrict__ gamma, const float* __restrict__ beta,
                          bf16* __restrict__ xn, const int* __restrict__ flag) {
    bool f32m = (*flag != 0);
    int wave = threadIdx.x >> 6;
    int lane = threadIdx.x & 63;
    int row  = blockIdx.x * 4 + wave;
    size_t base = xoff + (size_t)row * DMODEL;
    float v[6];
    float s = 0.f, s2 = 0.f;
#pragma unroll
    for (int i = 0; i < 6; ++i) {
        v[i] = ldx(x, base + lane + i * 64, f32m);
        s += v[i];
        s2 += v[i] * v[i];
    }
#pragma unroll
    for (int off = 32; off >= 1; off >>= 1) {
        s  += __shfl_down(s, off, 64);
        s2 += __shfl_down(s2, off, 64);
    }
    s  = __shfl(s, 0, 64);
    s2 = __shfl(s2, 0, 64);
    float mu   = s / DMODEL;
    float var  = s2 / DMODEL - mu * mu;
    float rstd = rsqrtf(var + 1e-5f);
    bf16* xnr = xn + (size_t)row * DMODEL;
#pragma unroll
    for (int i = 0; i < 6; ++i)
        xnr[lane + i * 64] = f2b((v[i] - mu) * rstd * gamma[lane + i * 64] + beta[lane + i * 64]);
}

// MFMA tile compute: 8 ds_read_b128 + 16 MFMA on one LDS buffer
__device__ __forceinline__ void compute_tile(const bf16 (*Al)[32], const bf16 (*Bl)[32],
                                             frag_cd acc[4][4], int wm, int wn,
                                             int mr, int quad) {
    frag_ab af[4], bfr[4];
#pragma unroll
    for (int r = 0; r < 4; ++r)
        af[r] = *(const frag_ab*)&Al[wm * 64 + r * 16 + mr][quad * 8];
#pragma unroll
    for (int c = 0; c < 4; ++c)
        bfr[c] = *(const frag_ab*)&Bl[wn * 64 + c * 16 + mr][quad * 8];
#pragma unroll
    for (int r = 0; r < 4; ++r)
#pragma unroll
        for (int c = 0; c < 4; ++c)
            acc[r][c] = __builtin_amdgcn_mfma_f32_16x16x32_bf16(af[r], bfr[c], acc[r][c], 0, 0, 0);
}

// ------------------------------------------------------------------
// MFMA bf16 GEMM, 128x128 tile, BK=32, 256 threads (2x2 waves of 64x64).
// C[M,N] = A[M,K] @ W[N,K]^T.  Double-buffered gld16 pipeline (R6).
// R7: XCD-aware 1-D grid decode (verified: FETCH 62->36MB on gate).
// MODE 1: gate epilogue -> d_out.   MODE 2: f32 store, 56 valid cols.
// MODE 4: in-proj combined: xi bf16 | silu(z) bf16.
// MODE 5: out-proj, A-staging multiplies a = ydir * sz (bf16).
// ------------------------------------------------------------------
template <int MODE>
__global__ __launch_bounds__(256) void gemm_mfma(
    const bf16* __restrict__ A, const bf16* __restrict__ W,
    int K, int lda, int ldw, int nNT,
    bf16* __restrict__ C, int ldc, int cofs,
    float* __restrict__ Cf, bf16* __restrict__ Cz, const bf16* __restrict__ Sz,
    const float* __restrict__ gb, const void* __restrict__ xg, size_t xoff,
    void* __restrict__ outg, const int* __restrict__ flag) {
    __shared__ bf16 Als[2][128][32];
    __shared__ bf16 Bls[2][128][32];
    int tid = threadIdx.x;
    int lane = tid & 63;
    int w = tid >> 6;
    int wm = w & 1, wn = w >> 1;
    // XCD-aware decode (see header comment)
    int wgid = blockIdx.x;
    int mt_lo = wgid & 7;
    int rr_ = wgid >> 3;
    int nt = rr_ % nNT;
    int mt = (rr_ / nNT) * 8 + mt_lo;
    int m0 = mt * 128, n0 = nt * 128;
    int row = tid >> 2, kc = tid & 3;
    int mr = lane & 15, quad = lane >> 4;

    const bf16* Ab0 = A + (size_t)(m0 + row) * lda + kc * 8;
    const bf16* Ab1 = A + (size_t)(m0 + 64 + row) * lda + kc * 8;
    const bf16* Wb0 = W + (size_t)(n0 + row) * ldw + kc * 8;
    const bf16* Wb1 = W + (size_t)(n0 + 64 + row) * ldw + kc * 8;
    const bf16* Zb0 = (MODE == 5) ? (Sz + (size_t)(m0 + row) * DINNER + kc * 8) : nullptr;
    const bf16* Zb1 = (MODE == 5) ? (Sz + (size_t)(m0 + 64 + row) * DINNER + kc * 8) : nullptr;

    frag_cd acc[4][4] = {};
    const int NT = K / 32;   // always even (12 or 24)

    if (MODE == 5) {
        uint4 eya0, eya1, esz0, esz1;   // even-tile regs
        uint4 oya0, oya1, osz0, osz1;   // odd-tile regs
        eya0 = *(const uint4*)(Ab0);      eya1 = *(const uint4*)(Ab1);
        esz0 = *(const uint4*)(Zb0);      esz1 = *(const uint4*)(Zb1);
        oya0 = *(const uint4*)(Ab0 + 32); oya1 = *(const uint4*)(Ab1 + 32);
        osz0 = *(const uint4*)(Zb0 + 32); osz1 = *(const uint4*)(Zb1 + 32);
        // prologue: tile 0 into buf 0
        *(uint4*)&Als[0][row][kc * 8]      = bmul8(eya0, esz0);
        *(uint4*)&Als[0][64 + row][kc * 8] = bmul8(eya1, esz1);
        gld16(&Bls[0][row][kc * 8], Wb0);
        gld16(&Bls[0][64 + row][kc * 8], Wb1);
        __syncthreads();
        for (int t = 0; t < NT; t += 2) {
            int k1 = (t + 1) * 32, k2 = (t + 2) * 32, k3 = (t + 3) * 32;
            *(uint4*)&Als[1][row][kc * 8]      = bmul8(oya0, osz0);
            *(uint4*)&Als[1][64 + row][kc * 8] = bmul8(oya1, osz1);
            gld16(&Bls[1][row][kc * 8], Wb0 + k1);
            gld16(&Bls[1][64 + row][kc * 8], Wb1 + k1);
            if (t + 2 < NT) {
                eya0 = *(const uint4*)(Ab0 + k2); eya1 = *(const uint4*)(Ab1 + k2);
                esz0 = *(const uint4*)(Zb0 + k2); esz1 = *(const uint4*)(Zb1 + k2);
            }
            compute_tile(Als[0], Bls[0], acc, wm, wn, mr, quad);
            __syncthreads();
            if (t + 2 < NT) {
                *(uint4*)&Als[0][row][kc * 8]      = bmul8(eya0, esz0);
                *(uint4*)&Als[0][64 + row][kc * 8] = bmul8(eya1, esz1);
                gld16(&Bls[0][row][kc * 8], Wb0 + k2);
                gld16(&Bls[0][64 + row][kc * 8], Wb1 + k2);
                oya0 = *(const uint4*)(Ab0 + k3); oya1 = *(const uint4*)(Ab1 + k3);
                osz0 = *(const uint4*)(Zb0 + k3); osz1 = *(const uint4*)(Zb1 + k3);
            }
            compute_tile(Als[1], Bls[1], acc, wm, wn, mr, quad);
            __syncthreads();
        }
    } else {
        gld16(&Als[0][row][kc * 8], Ab0);
        gld16(&Als[0][64 + row][kc * 8], Ab1);
        gld16(&Bls[0][row][kc * 8], Wb0);
        gld16(&Bls[0][64 + row][kc * 8], Wb1);
        __syncthreads();
        for (int t = 0; t < NT; t += 2) {
            int k1 = (t + 1) * 32, k2 = (t + 2) * 32;
            gld16(&Als[1][row][kc * 8], Ab0 + k1);
            gld16(&Als[1][64 + row][kc * 8], Ab1 + k1);
            gld16(&Bls[1][row][kc * 8], Wb0 + k1);
            gld16(&Bls[1][64 + row][kc * 8], Wb1 + k1);
            compute_tile(Als[0], Bls[0], acc, wm, wn, mr, quad);
            __syncthreads();
            if (t + 2 < NT) {
                gld16(&Als[0][row][kc * 8], Ab0 + k2);
                gld16(&Als[0][64 + row][kc * 8], Ab1 + k2);
                gld16(&Bls[0][row][kc * 8], Wb0 + k2);
                gld16(&Bls[0][64 + row][kc * 8], Wb1 + k2);
            }
            compute_tile(Als[1], Bls[1], acc, wm, wn, mr, quad);
            __syncthreads();
        }
    }

    bool f32m = (MODE == 1) ? (*flag != 0) : false;
#pragma unroll
    for (int r = 0; r < 4; ++r) {
#pragma unroll
        for (int c = 0; c < 4; ++c) {
#pragma unroll
            for (int reg = 0; reg < 4; ++reg) {
                int gm = m0 + wm * 64 + r * 16 + quad * 4 + reg;
                int gn = n0 + wn * 64 + c * 16 + mr;
                float v = acc[r][c][reg];
                if (MODE == 0 || MODE == 5) {
                    C[(size_t)gm * ldc + cofs + gn] = f2b(v);
                } else if (MODE == 2) {
                    if (gn < DTRANK + 2 * DSTATE) Cf[(size_t)gm * 56 + gn] = v;
                } else if (MODE == 4) {  // combined in-proj: xi | silu(z) bf16
                    if (gn < DINNER) {
                        C[(size_t)gm * DINNER + gn] = f2b(v);
                    } else {
                        float sz = v / (1.f + __expf(-v));
                        Cz[(size_t)gm * DINNER + (gn - DINNER)] = f2b(sz);
                    }
                } else {  // MODE 1 gate: g*yf + (1-g)*yb + x  (A == ycat)
                    float g   = 1.f / (1.f + __expf(-(v + gb[gn])));
                    float yfv = b2f(A[(size_t)gm * DINNER + gn]);
                    float ybv = b2f(A[(size_t)gm * DINNER + DMODEL + gn]);
                    size_t gi = xoff + (size_t)gm * DMODEL + gn;
                    float xv  = f32m ? ((const float*)xg)[gi] : b2f(((const bf16*)xg)[gi]);
                    float rr  = g * yfv + (1.f - g) * ybv + xv;
                    if (f32m) ((float*)outg)[gi] = rr;
                    else      ((bf16*)outg)[gi]  = f2b(rr);
                }
            }
        }
    }
}

// ------------------------------------------------------------------
// Depthwise conv + SiLU, bf16. R9-verified: 8 channels/thread, uint4.
// ------------------------------------------------------------------
__global__ void conv_kernel(const bf16* __restrict__ xi_buf, const float* __restrict__ cw,
                            const float* __restrict__ cb, bf16* __restrict__ xc, int reverse) {
    int g = blockIdx.x * blockDim.x + threadIdx.x;   // one per 8 channels
    int c8 = (g % (DINNER / 8)) * 8;
    int bl = g / (DINNER / 8);
    int l = bl % SEQ;
    int b = bl / SEQ;
    float4 wq[8];
#pragma unroll
    for (int j = 0; j < 8; ++j) wq[j] = *(const float4*)(cw + (c8 + j) * 4);
    float4 cb0 = *(const float4*)(cb + c8);
    float4 cb1 = *(const float4*)(cb + c8 + 4);
    float acc[8] = {cb0.x, cb0.y, cb0.z, cb0.w, cb1.x, cb1.y, cb1.z, cb1.w};

    const bf16* base = xi_buf + (size_t)b * SEQ * DINNER + c8;
#pragma unroll
    for (int k = 0; k < 4; ++k) {
        int ll = reverse ? (l + k) : (l - 3 + k);
        int wk = reverse ? (3 - k) : k;
        if (ll >= 0 && ll < SEQ) {
            uint4 v = *(const uint4*)(base + (size_t)ll * DINNER);
            const bf16* vb = (const bf16*)&v;
#pragma unroll
            for (int j = 0; j < 8; ++j)
                acc[j] += b2f(vb[j]) * ((const float*)&wq[j])[wk];
        }
    }
    uint4 out;
    bf16* ob = (bf16*)&out;
#pragma unroll
    for (int j = 0; j < 8; ++j)
        ob[j] = f2b(acc[j] / (1.f + __expf(-acc[j])));
    *(uint4*)(xc + (size_t)bl * DINNER + c8) = out;
}

// ------------------------------------------------------------------
// dt precompute (R4-verified): weights pinned in VGPRs, HW softplus.
// ------------------------------------------------------------------
__global__ __launch_bounds__(256, 4) void dt_kernel(const float* __restrict__ xp,
                                                    const float* __restrict__ dtwT,
                                                    const float* __restrict__ dtb,
                                                    float* __restrict__ dtf) {
    __shared__ float4 xps[DTR_R][6];   // 24 xp values per token
    int tid = threadIdx.x;
    int c = blockIdx.y * 256 + tid;
    float w[DTRANK];
#pragma unroll
    for (int r = 0; r < DTRANK; ++r) w[r] = dtwT[r * DINNER + c];
#pragma unroll
    for (int r = 0; r < DTRANK; ++r) asm volatile("" : "+v"(w[r]));  // pin in VGPRs
    float bias = dtb[c];

    size_t row0 = (size_t)blockIdx.x * DTR_R;
    for (int i = tid; i < DTR_R * 6; i += 256) {
        int s = i / 6, q = i % 6;
        xps[s][q] = *(const float4*)(xp + (row0 + s) * 56 + q * 4);
    }
    __syncthreads();

    for (int s = 0; s < DTR_R; s += 2) {
        float a0 = bias, a1 = bias;
#pragma unroll
        for (int q = 0; q < 6; ++q) {
            float4 x0 = xps[s][q];
            float4 x1 = xps[s + 1][q];
            a0 += x0.x * w[q * 4 + 0];  a1 += x1.x * w[q * 4 + 0];
            a0 += x0.y * w[q * 4 + 1];  a1 += x1.y * w[q * 4 + 1];
            a0 += x0.z * w[q * 4 + 2];  a1 += x1.z * w[q * 4 + 2];
            a0 += x0.w * w[q * 4 + 3];  a1 += x1.w * w[q * 4 + 3];
        }
        // hardware softplus: max(x,0) + ln2*log2(1 + 2^(-|x|*log2e))
        float e0 = __builtin_amdgcn_exp2f(fabsf(a0) * -1.44269504f);
        float e1 = __builtin_amdgcn_exp2f(fabsf(a1) * -1.44269504f);
        a0 = fmaxf(a0, 0.f) + 0.69314718f * __builtin_amdgcn_logf(1.f + e0);
        a1 = fmaxf(a1, 0.f) + 0.69314718f * __builtin_amdgcn_logf(1.f + e1);
        dtf[(row0 + s) * DINNER + c]     = a0;
        dtf[(row0 + s + 1) * DINNER + c] = a1;
    }
}

// ------------------------------------------------------------------
// Chunked selective scan, pointer-marching (R9-verified structure;
// R10's lane-half state-split raised total work -> reverted).
// R11: xps read as float4 (ds_read_b128) -- R9 asm issued 32 scalar
// ds_read_b32 per step (16 B + 16 C), ~1/3 of the ~205 issued
// instructions/step. 8 x b128 reads cut ~24 issue slots/step.
// ------------------------------------------------------------------
template <int PHASE>
__global__ void scan_phase(const float* __restrict__ xp, const bf16* __restrict__ xc,
                           const float* __restrict__ dtf, const float* __restrict__ Alog,
                           const float* __restrict__ Dg, float* __restrict__ states,
                           bf16* __restrict__ ydir, int reverse, const int* __restrict__ flag) {
    __shared__ __align__(16) float xps[16][32];
    bool generic = (flag[1] != 0);
    int tid = threadIdx.x;
    int bidx = blockIdx.x;
    int tc  = bidx % TC;
    int cgb = bidx / TC;       // bb*6+cg
    int cg  = cgb % 6;
    int bb  = cgb / 6;
    int c = cg * 128 + tid;

    float Av0 = -__expf(Alog[c * DSTATE]);
    float Av[DSTATE];
    if (generic) {
#pragma unroll
        for (int n = 0; n < DSTATE; ++n) Av[n] = -__expf(Alog[c * DSTATE + n]);
    }
    float Dv = Dg[c];

    float h[DSTATE];
    float Q = 1.f, Pg[DSTATE];
    size_t sbase = (size_t)bidx * 32;
    if (PHASE == 0) {
#pragma unroll
        for (int n = 0; n < DSTATE; ++n) { h[n] = 0.f; Pg[n] = 1.f; }
    } else {
#pragma unroll
        for (int n = 0; n < DSTATE; ++n) h[n] = states[(sbase + n) * 128 + tid];
    }

    const size_t brow = (size_t)bb * SEQ;
    const int t0 = tc * CL;
    const int tr0 = reverse ? (SEQ - 1 - t0) : t0;
    const long dstep = reverse ? -(long)DINNER : (long)DINNER;
    const float* pdt = dtf + (brow + tr0) * DINNER + c;
    const bf16*  pxc = xc  + (brow + tr0) * DINNER + c;
    bf16* pyd = (PHASE == 1) ? (ydir + (brow + tr0) * DINNER + c) : nullptr;

    for (int g0 = 0; g0 < CL; g0 += 16) {
        __syncthreads();
        for (int i = tid; i < 16 * 32; i += 128) {
            int s = i >> 5, r = i & 31;
            int t = t0 + g0 + s;
            int tr = reverse ? (SEQ - 1 - t) : t;
            xps[s][r] = xp[(brow + tr) * 56 + 24 + r];
        }
        __syncthreads();
        for (int s = 0; s < 16; ++s) {
            float dt  = *pdt;  pdt += dstep;
            float xcv = b2f(*pxc);  pxc += dstep;
            float dtx = dt * xcv;
            // vector LDS reads: B[0..15], C[0..15] as 8 x float4
            float4 B0 = *(const float4*)&xps[s][0];
            float4 B1 = *(const float4*)&xps[s][4];
            float4 B2 = *(const float4*)&xps[s][8];
            float4 B3 = *(const float4*)&xps[s][12];
            float Bv[DSTATE] = {B0.x, B0.y, B0.z, B0.w, B1.x, B1.y, B1.z, B1.w,
                                B2.x, B2.y, B2.z, B2.w, B3.x, B3.y, B3.z, B3.w};
            float accv = 0.f;
            if (PHASE == 1) {
                float4 C0 = *(const float4*)&xps[s][16];
                float4 C1 = *(const float4*)&xps[s][20];
                float4 C2 = *(const float4*)&xps[s][24];
                float4 C3 = *(const float4*)&xps[s][28];
                float Cv[DSTATE] = {C0.x, C0.y, C0.z, C0.w, C1.x, C1.y, C1.z, C1.w,
                                    C2.x, C2.y, C2.z, C2.w, C3.x, C3.y, C3.z, C3.w};
                if (!generic) {
                    float e1 = __expf(dt * Av0);
                    float d = e1;
#pragma unroll
                    for (int n = 0; n < DSTATE; ++n) {
                        h[n] = d * h[n] + dtx * Bv[n];
                        accv += h[n] * Cv[n];
                        d *= e1;
                    }
                } else {
#pragma unroll
                    for (int n = 0; n < DSTATE; ++n) {
                        float dA = __expf(dt * Av[n]);
                        h[n] = dA * h[n] + dtx * Bv[n];
                        accv += h[n] * Cv[n];
                    }
                }
                *pyd = f2b(accv + xcv * Dv);
                pyd += dstep;
            } else {
                if (!generic) {
                    float e1 = __expf(dt * Av0);
                    float d = e1;
#pragma unroll
                    for (int n = 0; n < DSTATE; ++n) {
                        h[n] = d * h[n] + dtx * Bv[n];
                        d *= e1;
                    }
                    Q *= e1;
                } else {
#pragma unroll
                    for (int n = 0; n < DSTATE; ++n) {
                        float dA = __expf(dt * Av[n]);
                        h[n] = dA * h[n] + dtx * Bv[n];
                        Pg[n] *= dA;
                    }
                }
            }
        }
    }
    if (PHASE == 0) {
        if (!generic) {
            float d = Q;
#pragma unroll
            for (int n = 0; n < DSTATE; ++n) { Pg[n] = d; d *= Q; }
        }
#pragma unroll
        for (int n = 0; n < DSTATE; ++n) {
            states[(sbase + n) * 128 + tid]      = Pg[n];
            states[(sbase + 16 + n) * 128 + tid] = h[n];
        }
    }
}

__global__ void scan_stitch(float* __restrict__ states) {
    int tid = threadIdx.x;
    int cgb = blockIdx.x;
    float h[DSTATE];
#pragma unroll
    for (int n = 0; n < DSTATE; ++n) h[n] = 0.f;
    for (int tc = 0; tc < TC; ++tc) {
        size_t base = ((size_t)cgb * TC + tc) * 32;
#pragma unroll
        for (int n = 0; n < DSTATE; ++n) {
            float Pv = states[(base + n) * 128 + tid];
            float ev = states[(base + 16 + n) * 128 + tid];
            states[(base + n) * 128 + tid] = h[n];   // h_in for this chunk
            h[n] = Pv * h[n] + ev;
        }
    }
}

// ------------------------------------------------------------------
extern "C" void kernel_launch(void* const* d_in, const int* in_sizes, int n_in,
                              void* d_out, int out_size, void* d_ws, size_t ws_size,
                              hipStream_t stream) {
    (void)n_in; (void)out_size;
    bool dict_order = (in_sizes[4] < 2048);
    int fbase = dict_order ? 5 : 3;
    int bbase = dict_order ? 14 : 12;
    int gwi = dict_order ? 3 : 21;
    int gbi = dict_order ? 4 : 22;

    auto al = [](size_t b) { return (b + 255) & ~(size_t)255; };
    char* ws = (char*)d_ws;
    size_t off = 0;
    auto alloc = [&](size_t bytes) {
        void* p = ws + off;
        off += al(bytes);
        return p;
    };

    int* flag = (int*)alloc(256);

    CvtF pf{};
    int cf = 0;
    auto addf = [&](int idx, int n) {
        float* d = (float*)alloc((size_t)n * 4);
        pf.src[cf] = d_in[idx]; pf.dst[cf] = d; pf.n[cf] = n; ++cf;
        return d;
    };
    float* ln_gc   = addf(1, DMODEL);
    float* ln_bc   = addf(2, DMODEL);
    float* gate_bc = addf(gbi, DMODEL);
    float* convw_f[2], *convb_f[2], *dtw_f[2], *dtb_f[2], *alog_f[2], *dd_f[2];
    for (int d = 0; d < 2; ++d) {
        int base = d ? bbase : fbase;
        convw_f[d] = addf(base + 1, DINNER * 4);
        convb_f[d] = addf(base + 2, DINNER);
        dtw_f[d]   = addf(base + 4, DINNER * DTRANK);
        dtb_f[d]   = addf(base + 5, DINNER);
        alog_f[d]  = addf(base + 6, DINNER * DSTATE);
        dd_f[d]    = addf(base + 7, DINNER);
    }

    CvtB pb{};
    int cb = 0;
    auto addb = [&](int idx, int n, size_t alloc_n) {
        bf16* d = (bf16*)alloc(alloc_n * 2);
        pb.src[cb] = d_in[idx]; pb.dst[cb] = d; pb.n[cb] = n; ++cb;
        return d;
    };
    bf16* gate_wb = addb(gwi, DMODEL * 2 * DMODEL, (size_t)DMODEL * 2 * DMODEL);
    bf16 *inw_b[2], *xpw_b[2], *outw_b[2];
    for (int d = 0; d < 2; ++d) {
        int base = d ? bbase : fbase;
        inw_b[d]  = addb(base + 0, 2 * DINNER * DMODEL, (size_t)2 * DINNER * DMODEL);
        xpw_b[d]  = addb(base + 3, 56 * DINNER, (size_t)128 * DINNER);  // padded
        outw_b[d] = addb(base + 8, DMODEL * DINNER, (size_t)DMODEL * DINNER);
    }

    // transposed dt weights (f32, [24][768]) for coalesced dt_kernel
    float* dtwT_f[2];
    for (int d = 0; d < 2; ++d)
        dtwT_f[d] = (float*)alloc((size_t)DTRANK * DINNER * 4);

    size_t fixed = off;

    // per-chunk activations (silu(z) stored bf16)
    auto chunk_need = [&](int bc) {
        size_t T = (size_t)bc * SEQ;
        return al(T * DMODEL * 2)                       // xn
             + 2 * al(T * DINNER * 2)                   // xi(/ydir), xc
             + al(T * 56 * 4)                           // xp f32
             + al(T * DINNER * 4)                       // dt f32
             + al(T * DINNER * 2)                       // silu(z) bf16
             + al(T * DINNER * 2)                       // ycat
             + al((size_t)bc * 6 * TC * 32 * 128 * 4);  // scan states
    };
    int Bc = 32;
    while (Bc > 1 && fixed + chunk_need(Bc) > ws_size) Bc >>= 1;
    size_t T = (size_t)Bc * SEQ;
    int nMT = (int)(T / 128);   // M tiles; = 8*Bc, divisible by 8

    bf16*  xn_c   = (bf16*)alloc(T * DMODEL * 2);
    bf16*  xib    = (bf16*)alloc(T * DINNER * 2);
    bf16*  xcb    = (bf16*)alloc(T * DINNER * 2);
    float* xpb    = (float*)alloc(T * 56 * 4);
    float* dtfb   = (float*)alloc(T * DINNER * 4);
    bf16*  zbb    = (bf16*)alloc(T * DINNER * 2);
    bf16*  ycat   = (bf16*)alloc(T * DINNER * 2);
    float* states = (float*)alloc((size_t)Bc * 6 * TC * 32 * 128 * 4);
    bf16*  ydir   = xib;  // alias: xi dead after conv

    hipMemsetAsync(flag, 0, 8, stream);
    for (int d = 0; d < 2; ++d)
        hipMemsetAsync(xpw_b[d], 0, (size_t)128 * DINNER * 2, stream);
    detect_kernel<<<1, 256, 0, stream>>>((const unsigned short*)d_in[0], flag);
    convert_f_kernel<<<dim3(8, 15), 256, 0, stream>>>(pf, flag);
    convert_b_kernel<<<dim3(32, 7), 256, 0, stream>>>(pb, flag);
    struct_check<<<3, 256, 0, stream>>>(alog_f[0], flag);
    struct_check<<<3, 256, 0, stream>>>(alog_f[1], flag);
    for (int d = 0; d < 2; ++d)
        transpose_dtw<<<(DINNER * DTRANK + 255) / 256, 256, 0, stream>>>(dtw_f[d], dtwT_f[d]);

    for (int c0 = 0; c0 < BATCH; c0 += Bc) {
        size_t tok0 = (size_t)c0 * SEQ;

        ln_kernel<<<(unsigned)(T / 4), 256, 0, stream>>>(
            d_in[0], tok0 * DMODEL, ln_gc, ln_bc, xn_c, flag);

        for (int dir = 0; dir < 2; ++dir) {
            // combined in-proj: xi (bf16) + silu(z) (bf16), nNT=12
            gemm_mfma<4><<<nMT * 12, 256, 0, stream>>>(
                xn_c, inw_b[dir], DMODEL, DMODEL, DMODEL, 12,
                xib, DINNER, 0, nullptr, zbb, nullptr,
                nullptr, nullptr, 0, nullptr, flag);
            conv_kernel<<<(unsigned)((T * DINNER) / 2048), 256, 0, stream>>>(
                xib, convw_f[dir], convb_f[dir], xcb, dir);
            // x-proj (56 cols padded to 128), nNT=1
            gemm_mfma<2><<<nMT * 1, 256, 0, stream>>>(
                xcb, xpw_b[dir], DINNER, DINNER, DINNER, 1,
                nullptr, 0, 0, xpb, nullptr, nullptr,
                nullptr, nullptr, 0, nullptr, flag);
            dt_kernel<<<dim3((unsigned)(T / DTR_R), 3), 256, 0, stream>>>(
                xpb, dtwT_f[dir], dtb_f[dir], dtfb);
            // chunked scan
            scan_phase<0><<<Bc * 6 * TC, 128, 0, stream>>>(
                xpb, xcb, dtfb, alog_f[dir], dd_f[dir], states, nullptr, dir, flag);
            scan_stitch<<<Bc * 6, 128, 0, stream>>>(states);
            scan_phase<1><<<Bc * 6 * TC, 128, 0, stream>>>(
                xpb, xcb, dtfb, alog_f[dir], dd_f[dir], states, ydir, dir, flag);
            // out-proj with fused a = ydir * sz; nNT=3
            gemm_mfma<5><<<nMT * 3, 256, 0, stream>>>(
                ydir, outw_b[dir], DINNER, DINNER, DINNER, 3,
                ycat, DINNER, dir * DMODEL, nullptr, nullptr, zbb,
                nullptr, nullptr, 0, nullptr, flag);
        }

        // gate GEMM + combine + residual, nNT=3
        gemm_mfma<1><<<nMT * 3, 256, 0, stream>>>(
            ycat, gate_wb, DINNER, DINNER, DINNER, 3,
            nullptr, 0, 0, nullptr, nullptr, nullptr,
            gate_bc, d_in[0], tok0 * DMODEL, d_out, flag);
    }
}